// Round 18
// baseline (431.387 us; speedup 1.0000x reference)
//
#include <hip/hip_runtime.h>
#include <math.h>

#define B_ 2
#define S_ 2048
#define H_ 16
#define DH_ 64
#define D_ 1024
#define MEM_ 1000
#define KT_ 10
#define THRESH_ 0.5
#define BS_ (B_ * S_)
#define EVCAP_ (2 * S_)   // max possible events (<= S per sample)

typedef float f32x4 __attribute__((ext_vector_type(4)));
typedef short bf16x8 __attribute__((ext_vector_type(8)));
typedef short s16x4 __attribute__((ext_vector_type(4)));

__device__ inline unsigned short f2bf(float f) {
    union { float f; unsigned u; } v; v.f = f;
    unsigned u = v.u;
    unsigned r = (u + 0x7FFFu + ((u >> 16) & 1u)) >> 16;  // RNE
    return (unsigned short)r;
}
__device__ inline float bf2f(unsigned short h) {
    union { unsigned u; float f; } v; v.u = ((unsigned)h) << 16; return v.f;
}

// async global->LDS, 16B per lane; LDS dest = wave-uniform base + lane*16
__device__ __forceinline__ void gload16(const short* gp, const short* lp) {
    __builtin_amdgcn_global_load_lds(
        (__attribute__((address_space(1))) void*)(unsigned long long)gp,
        (__attribute__((address_space(3))) void*)(unsigned)(unsigned long long)lp,
        16, 0, 0);
}

// ---------------- fused input split: X (h,m,l) + 4 weights in ONE dispatch ----
struct SpArgs {
    const float* X;
    short *Xh, *Xm, *Xl;
    const float* W[4];          // Wq, Wk, Wv, Wo
    short *Wh[4], *Wm[4], *Wl[4];  // Wl null -> skip
    int nx4;                    // X f32x4 count (4096 blocks worth)
};
__global__ __launch_bounds__(256) void split_all_kernel(SpArgs sa)
{
    int bid = blockIdx.x;
    const float* src; short *ph, *pm, *pl; int i;
    if (bid < 4096) {               // X section
        i = bid * 256 + threadIdx.x;
        if (i >= sa.nx4) return;
        src = sa.X; ph = sa.Xh; pm = sa.Xm; pl = sa.Xl;
    } else {                        // weight section: 1024 blocks each
        int wb = bid - 4096;
        int y = wb >> 10;
        i = (wb & 1023) * 256 + threadIdx.x;
        src = sa.W[y]; ph = sa.Wh[y]; pm = sa.Wm[y]; pl = sa.Wl[y];
    }
    float4 x = ((const float4*)src)[i];
    float xs[4] = {x.x, x.y, x.z, x.w};
    s16x4 hv, mv, lv;
    bool wl = (pl != nullptr);
#pragma unroll
    for (int j = 0; j < 4; ++j) {
        unsigned short hb = f2bf(xs[j]);
        float hf = bf2f(hb);
        float r1 = xs[j] - hf;            // exact in f32
        unsigned short mb = f2bf(r1);
        hv[j] = (short)hb; mv[j] = (short)mb;
        if (wl) {
            float mf = bf2f(mb);
            lv[j] = (short)f2bf(r1 - mf); // exact residual, rounded
        }
    }
    ((s16x4*)ph)[i] = hv;
    ((s16x4*)pm)[i] = mv;
    if (wl) ((s16x4*)pl)[i] = lv;
}

// ---------------- 256x256 single-phase split-precision bf16 MFMA GEMM ----------
// BK=32, FOUR LDS buffers (128 KiB), 3 tiles in flight, counted vmcnt(8):
// HBM latency cover = 2 tiles (~1470cy) > ~900cy. Per tile: 12 ds_read_b128 +
// stage(t+3) + 32 MFMA + counted vmcnt + ONE barrier.
struct G8Args {
    const short* A[4][3];   // per-group A term pointers (term id = gs>>5)
    const short* B[4][3];
    short* outb[4];         // bf16 output (or null)
    float* outf[4];         // f32 output (used when outb[g]==null)
    int gsbase[4];          // global K-step (32-wide) base per group
    int nt;                 // K-tiles per block (>= 3)
};

__global__ __launch_bounds__(512, 2) void gemm8(G8Args ga)
{
    __shared__ __align__(16) short Abuf[4][2][4096];   // [buf][half(128 rows)][packed 128x32]
    __shared__ __align__(16) short Bbuf[4][2][4096];

    int wg = blockIdx.x;
    int lin = (wg & 7) * 32 + (wg >> 3);   // XCD-clustered (256 % 8 == 0 -> bijective)
    int jb = lin >> 4;                     // (g, bcol): 2 per XCD -> B panels L2-resident
    int by = lin & 15;                     // row panel 0..15
    int g = jb >> 2;
    int bcol = jb & 3;

    int tid = threadIdx.x;
    int w = tid >> 6, l = tid & 63;
    int wm = w >> 2, wn = w & 3;           // wave grid 2M x 4N
    int lg = l >> 4, lc = l & 15;

    const short* A0 = ga.A[g][0]; const short* A1 = ga.A[g][1]; const short* A2 = ga.A[g][2];
    const short* B0 = ga.B[g][0]; const short* B1 = ga.B[g][1]; const short* B2 = ga.B[g][2];
    const int gs0 = ga.gsbase[g];
    const int NT = ga.nt;

    const int u = tid;
    const int vswz = (u & 7) ^ ((u >> 3) & 7);
    const int srow = 2 * (u >> 3) + (vswz >> 2);     // 0..127 within half
    const int skcol = (vswz & 3) * 8;                // shorts
    const size_t abase = (size_t)(by * 256) * D_ + skcol;
    const size_t bbase = (size_t)(bcol * 256) * D_ + skcol;
    const int dst0 = w * 512;                        // wave-uniform LDS short offset

    auto STAGE = [&](int ts, int d) {
        int tt = ts >> 5; int k0 = (ts & 31) << 5;
        const short* At = (tt == 0) ? A0 : ((tt == 1) ? A1 : A2);
        const short* Bt = (tt == 0) ? B0 : ((tt == 1) ? B1 : B2);
        const short* Ab = At + abase + k0;
        const short* Bb = Bt + bbase + k0;
#pragma unroll
        for (int h = 0; h < 2; ++h) {
            gload16(Ab + (size_t)(h * 128 + srow) * D_, &Abuf[d][h][dst0]);
            gload16(Bb + (size_t)(h * 128 + srow) * D_, &Bbuf[d][h][dst0]);
        }
    };   // 4 vmcnt increments per tile

    f32x4 acc[8][4] = {};
    const int psa = (((((lc & 1) << 2) | lg)) ^ ((lc >> 1) & 7)) * 8;
    const int rbase = (lc >> 1) * 64;

    // prologue: stage tiles 0,1,2 (12 loads in flight)
    STAGE(gs0, 0);
    STAGE(gs0 + 1, 1);
    STAGE(gs0 + 2, 2);
    asm volatile("s_waitcnt vmcnt(8)" ::: "memory");   // tile 0 landed; 1,2 in flight
    asm volatile("s_barrier" ::: "memory");
    __builtin_amdgcn_sched_barrier(0);

    for (int t = 0; t < NT; ++t) {
        int d = t & 3;
        const short* Ab0 = &Abuf[d][wm][rbase + psa];
        const short* Bb0 = &Bbuf[d][wn >> 1][(wn & 1) * 2048 + rbase + psa];
        bf16x8 av[8], bv[4];
#pragma unroll
        for (int nf = 0; nf < 4; ++nf) bv[nf] = *(const bf16x8*)&Bb0[nf * 512];
#pragma unroll
        for (int mf = 0; mf < 8; ++mf) av[mf] = *(const bf16x8*)&Ab0[mf * 512];
        if (t + 3 < NT) STAGE(gs0 + t + 3, (t + 3) & 3);
        __builtin_amdgcn_s_setprio(1);
#pragma unroll
        for (int mf = 0; mf < 8; ++mf)
#pragma unroll
            for (int nf = 0; nf < 4; ++nf)
                acc[mf][nf] = __builtin_amdgcn_mfma_f32_16x16x32_bf16(av[mf], bv[nf], acc[mf][nf], 0, 0, 0);
        __builtin_amdgcn_s_setprio(0);
        // need tile t+1 landed before next iteration reads it
        if (t + 3 < NT)      asm volatile("s_waitcnt vmcnt(8)" ::: "memory");  // t+2,t+3 stay in flight
        else if (t + 2 < NT) asm volatile("s_waitcnt vmcnt(4)" ::: "memory");  // t+2 stays in flight
        else if (t + 1 < NT) asm volatile("s_waitcnt vmcnt(0)" ::: "memory");  // drain tail
        asm volatile("s_barrier" ::: "memory");
        __builtin_amdgcn_sched_barrier(0);
    }

    // epilogue
    short* ob = ga.outb[g];
    if (ob) {
#pragma unroll
        for (int mf = 0; mf < 8; ++mf)
#pragma unroll
            for (int nf = 0; nf < 4; ++nf)
#pragma unroll
                for (int reg = 0; reg < 4; ++reg) {
                    int row = by * 256 + wm * 128 + mf * 16 + lg * 4 + reg;
                    int col = bcol * 256 + wn * 64 + nf * 16 + lc;
                    ob[(size_t)row * D_ + col] = (short)f2bf(acc[mf][nf][reg]);
                }
    } else {
        float* of = ga.outf[g];
#pragma unroll
        for (int mf = 0; mf < 8; ++mf)
#pragma unroll
            for (int nf = 0; nf < 4; ++nf)
#pragma unroll
                for (int reg = 0; reg < 4; ++reg) {
                    int row = by * 256 + wm * 128 + mf * 16 + lg * 4 + reg;
                    int col = bcol * 256 + wn * 64 + nf * 16 + lc;
                    of[(size_t)row * D_ + col] = acc[mf][nf][reg];
                }
    }
}

// ---------------- fused post-QVK: V transpose + K split-K add (one dispatch) ----
__global__ __launch_bounds__(256) void fixup_kernel(const short* __restrict__ vbf,
                                                    short* __restrict__ vbfT,
                                                    float* __restrict__ kf,
                                                    const float* __restrict__ kp1,
                                                    short* __restrict__ kbf)
{
    int bid = blockIdx.x;
    int tid = threadIdx.x;
    if (bid < 1024) {
        __shared__ short st[64][70];
        int t = bid;
        int s0 = (t & 31) * 64;
        int h = (t >> 5) & 15;
        int b = t >> 9;
        int r = tid >> 2, cb = (tid & 3) * 16;
        const short* src = vbf + (size_t)(b * S_ + s0 + r) * D_ + h * DH_ + cb;
        *(bf16x8*)&st[r][cb] = *(const bf16x8*)src;
        *(bf16x8*)&st[r][cb + 8] = *(const bf16x8*)(src + 8);
        __syncthreads();
        int c = tid >> 2, sb = (tid & 3) * 16;
        short tmp[16];
#pragma unroll
        for (int i = 0; i < 16; ++i) tmp[i] = st[sb + i][c];
        short* dst = vbfT + ((size_t)(b * H_ + h) * DH_ + c) * S_ + s0 + sb;
        *(bf16x8*)dst = *(bf16x8*)&tmp[0];
        *(bf16x8*)(dst + 8) = *(bf16x8*)&tmp[8];
    } else {
        size_t i = (size_t)(bid - 1024) * 256 + tid;
        float4 a = ((const float4*)kf)[i];
        float4 b = ((const float4*)kp1)[i];
        float4 s = {a.x + b.x, a.y + b.y, a.z + b.z, a.w + b.w};
        ((float4*)kf)[i] = s;
        s16x4 o;
        o[0] = (short)f2bf(s.x); o[1] = (short)f2bf(s.y);
        o[2] = (short)f2bf(s.z); o[3] = (short)f2bf(s.w);
        ((s16x4*)kbf)[i] = o;
    }
}

__global__ __launch_bounds__(256) void addo4_kernel(const float* __restrict__ p0,
                                                    const float* __restrict__ p1,
                                                    const float* __restrict__ p2,
                                                    const float* __restrict__ p3,
                                                    float* __restrict__ out)
{
    size_t i = (size_t)blockIdx.x * 256 + threadIdx.x;
    float4 a = ((const float4*)p0)[i];
    float4 b = ((const float4*)p1)[i];
    float4 c = ((const float4*)p2)[i];
    float4 d = ((const float4*)p3)[i];
    float4 s = {((a.x + b.x) + c.x) + d.x, ((a.y + b.y) + c.y) + d.y,
                ((a.z + b.z) + c.z) + d.z, ((a.w + b.w) + c.w) + d.w};
    ((float4*)out)[i] = s;
}

// ---------------- surprise (both batches): sur[b][t] = ||kf[t]-kf[t-1]|| ----------
__global__ __launch_bounds__(256) void surprise_kernel(const float* __restrict__ kf,
                                                       double* __restrict__ sur)
{
    int t = blockIdx.x;
    int b = blockIdx.y;
    if (t == 0) { if (threadIdx.x == 0) sur[(size_t)b * S_] = 0.0; return; }
    const float* kfb = kf + (size_t)b * S_ * D_;
    __shared__ double red[256];
    double acc = 0.0;
    for (int d = threadIdx.x; d < D_; d += 256) {
        double df = (double)kfb[(size_t)t * D_ + d] - (double)kfb[(size_t)(t - 1) * D_ + d];
        acc += df * df;
    }
    red[threadIdx.x] = acc;
    __syncthreads();
    for (int s = 128; s > 0; s >>= 1) {
        if (threadIdx.x < s) red[threadIdx.x] += red[threadIdx.x + s];
        __syncthreads();
    }
    if (threadIdx.x == 0) sur[(size_t)b * S_ + t] = sqrt(red[0]);
}

// ---------------- boundaries BOTH batches (single block; batch loop preserves
// the reference's sequential FIFO semantics). scal: [4+b]=nseg_b, [6+b]=evbase_b.
__global__ __launch_bounds__(256) void boundary2_kernel(const double* __restrict__ sur,
                                                        int* __restrict__ seg_start,
                                                        int* __restrict__ seg_end,
                                                        int* __restrict__ scal)
{
    __shared__ double lsur[S_];
    __shared__ double red[256];
    __shared__ double sh_mean, sh_thr;
    __shared__ int cnt[256];
    int tid = threadIdx.x;
    int running = 0;
    for (int b = 0; b < B_; ++b) {
        __syncthreads();
        for (int t = tid; t < S_; t += 256) lsur[t] = sur[(size_t)b * S_ + t];
        __syncthreads();
        double a = 0.0;
        for (int t = tid; t < S_; t += 256) a += lsur[t];
        red[tid] = a;
        __syncthreads();
        for (int s = 128; s > 0; s >>= 1) {
            if (tid < s) red[tid] += red[tid + s];
            __syncthreads();
        }
        if (tid == 0) sh_mean = red[0] / (double)S_;
        __syncthreads();
        double mean = sh_mean;
        a = 0.0;
        for (int t = tid; t < S_; t += 256) { double d = lsur[t] - mean; a += d * d; }
        red[tid] = a;
        __syncthreads();
        for (int s = 128; s > 0; s >>= 1) {
            if (tid < s) red[tid] += red[tid + s];
            __syncthreads();
        }
        if (tid == 0) sh_thr = mean + THRESH_ * sqrt(red[0] / (double)(S_ - 1));
        __syncthreads();
        double thr = sh_thr;
        bool flg[8];
        int c = 0;
#pragma unroll
        for (int j = 0; j < 8; ++j) {
            int t = tid * 8 + j;
            flg[j] = (lsur[t] > thr) || (t == S_ - 1);
            c += flg[j] ? 1 : 0;
        }
        cnt[tid] = c;
        __syncthreads();
        for (int off = 1; off < 256; off <<= 1) {   // Hillis-Steele inclusive scan
            int v = cnt[tid];
            int add = (tid >= off) ? cnt[tid - off] : 0;
            __syncthreads();
            cnt[tid] = v + add;
            __syncthreads();
        }
        int r = (tid == 0) ? 0 : cnt[tid - 1];
        int* se = seg_end + b * S_;
        int* ss = seg_start + b * S_;
#pragma unroll
        for (int j = 0; j < 8; ++j) {
            if (flg[j]) { se[r] = tid * 8 + j; ++r; }
        }
        __syncthreads();
        int n = cnt[255];
        for (int i = tid; i < n; i += 256)
            ss[i] = (i == 0) ? 0 : se[i - 1] + 1;
        if (tid == 0) {
            scal[4 + b] = n;        // nseg_b
            scal[6 + b] = running;  // evbase_b
        }
        running += n;
        __syncthreads();
    }
}

// ---------------- segment means BOTH batches -> append events ----------------
__global__ __launch_bounds__(256) void seg_means_kernel(const float* __restrict__ kf,
                                                        float* __restrict__ events,
                                                        const int* __restrict__ seg_start,
                                                        const int* __restrict__ seg_end,
                                                        const int* __restrict__ scal)
{
    int g = blockIdx.x;
    int b = blockIdx.y;
    if (g >= scal[4 + b]) return;
    const float* kfb = kf + (size_t)b * S_ * D_;
    int s = seg_start[b * S_ + g], e = seg_end[b * S_ + g];
    double inv = 1.0 / (double)(e - s + 1);
    size_t obase = (size_t)(scal[6 + b] + g) * D_;
    for (int d = threadIdx.x; d < D_; d += 256) {
        double acc = 0.0;
        for (int r = s; r <= e; ++r) acc += (double)kfb[(size_t)r * D_ + d];
        events[obase + d] = (float)(acc * inv);
    }
}

// ---------------- cosine sims BOTH batches vs each batch's last key ----------
__global__ __launch_bounds__(256) void sims_kernel(const float* __restrict__ events,
                                                   const float* __restrict__ kf,
                                                   float* __restrict__ sims,
                                                   const int* __restrict__ scal)
{
    int e = blockIdx.x;
    int b = blockIdx.y;
    int total = scal[6 + b] + scal[4 + b];   // events appended through batch b
    int w = total < MEM_ ? total : MEM_;
    float* sb = sims + b * MEM_;
    if (e >= w) { if (threadIdx.x == 0) sb[e] = -INFINITY; return; }
    int wstart = total - w;
    const float* ev = events + (size_t)(wstart + e) * D_;
    const float* q = kf + ((size_t)(b * S_ + S_ - 1)) * D_;
    __shared__ double r1[256], r2[256], r3[256];
    int tid = threadIdx.x;
    double dot = 0.0, n2 = 0.0, q2 = 0.0;
    for (int d = tid; d < D_; d += 256) {
        double ed = ev[d], qd = q[d];
        dot += ed * qd; n2 += ed * ed; q2 += qd * qd;
    }
    r1[tid] = dot; r2[tid] = n2; r3[tid] = q2;
    __syncthreads();
    for (int s = 128; s > 0; s >>= 1) {
        if (tid < s) { r1[tid] += r1[tid + s]; r2[tid] += r2[tid + s]; r3[tid] += r3[tid + s]; }
        __syncthreads();
    }
    if (tid == 0) {
        double mn = sqrt(r2[0]); if (mn < 1e-8) mn = 1e-8;
        double qn = sqrt(r3[0]); if (qn < 1e-8) qn = 1e-8;
        sb[e] = (float)(r1[0] / (mn * qn));
    }
}

// ---------------- top-KT BOTH batches (block b) + gather ----------------
__global__ __launch_bounds__(256) void topk_kernel(const float* __restrict__ events,
                                                   float* __restrict__ sims,
                                                   float* __restrict__ ret,
                                                   const int* __restrict__ scal)
{
    int b = blockIdx.x;
    int total = scal[6 + b] + scal[4 + b];
    int w = total < MEM_ ? total : MEM_;
    int wstart = total - w;
    float* sb = sims + b * MEM_;
    float* retb = ret + (size_t)b * KT_ * D_;
    __shared__ float bv[256];
    __shared__ int bidx[256];
    __shared__ int chosen;
    int tid = threadIdx.x;
    for (int r = 0; r < KT_; ++r) {
        float best = -INFINITY;
        int bi = 0x7fffffff;
        for (int e = tid; e < w; e += 256) {
            float v = sb[e];
            if (v > best || (v == best && e < bi)) { best = v; bi = e; }
        }
        bv[tid] = best; bidx[tid] = bi;
        __syncthreads();
        for (int s = 128; s > 0; s >>= 1) {
            if (tid < s) {
                if (bv[tid + s] > bv[tid] || (bv[tid + s] == bv[tid] && bidx[tid + s] < bidx[tid])) {
                    bv[tid] = bv[tid + s]; bidx[tid] = bidx[tid + s];
                }
            }
            __syncthreads();
        }
        if (tid == 0) {
            chosen = (r < w) ? bidx[0] : -1;
            if (chosen >= 0) sb[chosen] = -INFINITY;
        }
        __syncthreads();
        int c = chosen;
        if (c >= 0) {
            const float* ev = events + (size_t)(wstart + c) * D_;
            for (int d = tid; d < D_; d += 256) retb[(size_t)r * D_ + d] = ev[d];
        } else {
            for (int d = tid; d < D_; d += 256) retb[(size_t)r * D_ + d] = 0.0f;
        }
        __syncthreads();
    }
}

// ---------------- attention: bf16 MFMA flash, QTT=128, KTT=128, peeled memtile ----
#define QTT 128
#define KTT 128
__global__ __launch_bounds__(512, 4) void attn_mfma_kernel(const short* __restrict__ qbf,
                                                           const short* __restrict__ kbf,
                                                           const short* __restrict__ vbfT,
                                                           const float* __restrict__ ret,
                                                           const int* __restrict__ amask,
                                                           short* __restrict__ AOh,
                                                           short* __restrict__ AOm)
{
    __shared__ __align__(16) short k_s[KTT][72];       // [key][d]   (row 144B)
    __shared__ __align__(16) short vT_s[DH_][136];     // [d][key]   (row 272B)
    __shared__ __align__(16) short p_s[8][16][136];    // per-wave [q][key]

    const float LOG2E = 1.4426950408889634f;
    int bid = blockIdx.x;                    // 0..511
    int xcd = bid & 7;
    int idx = bid >> 3;                      // 0..63
    int qtslot = idx >> 2;                   // 0..15
    int hbL = idx & 3;                       // 0..3
    int qt = (qtslot < 8) ? (15 - qtslot) : (qtslot - 8);
    int hb = xcd * 4 + hbL;                  // 0..31
    int h = hb & 15, b = hb >> 4;
    int q0 = qt * QTT;

    int tid = threadIdx.x;
    int w = tid >> 6, l = tid & 63;          // 8 waves
    int lg = l >> 4, lc = l & 15;
    int qb = q0 + w * 16;                    // this wave's 16 queries
    float scale2 = 0.125f * LOG2E;
    float slope2 = exp2f(-0.5f * (float)(h + 1)) * LOG2E;

    bf16x8 qfr[2];
#pragma unroll
    for (int half = 0; half < 2; ++half)
        qfr[half] = *(const bf16x8*)(qbf + ((size_t)(b * S_ + qb + lc)) * D_ + h * DH_ + half * 32 + lg * 8);

    float mrow[4], lrow[4], fac[4];
#pragma unroll
    for (int r = 0; r < 4; ++r) { mrow[r] = -INFINITY; lrow[r] = 0.0f; }
    f32x4 O[4] = {};

    // main-loop staging indices
    int skr = tid >> 2;             // K stage: key row 0..127
    int skc = (tid & 3) * 16;       // K stage: d col base (16 shorts)
    int sdv = tid >> 3;             // V stage: d row 0..63
    int skk = (tid & 7) * 16;       // V stage: key col base (16 shorts)

    const short* kptr = kbf + ((size_t)(b * S_ + skr)) * D_ + h * DH_ + skc;
    const short* vptr = vbfT + ((size_t)(b * H_ + h) * DH_ + sdv) * S_ + skk;

    int ntiles = qt + 1;            // K-tiles of 128 keys
    bf16x8 kr0 = *(const bf16x8*)kptr, kr1 = *(const bf16x8*)(kptr + 8);
    bf16x8 vr0 = *(const bf16x8*)vptr, vr1 = *(const bf16x8*)(vptr + 8);

    for (int tile = 0; tile < ntiles; ++tile) {
        int j0 = tile * KTT;
        __syncthreads();   // all readers of previous tile done
        *(bf16x8*)&k_s[skr][skc] = kr0;
        *(bf16x8*)&k_s[skr][skc + 8] = kr1;
        *(bf16x8*)&vT_s[sdv][skk] = vr0;
        *(bf16x8*)&vT_s[sdv][skk + 8] = vr1;
        __syncthreads();   // tile visible
        if (tile + 1 < ntiles) {   // prefetch next tile (latency hidden under compute)
            const short* kp = kptr + (size_t)(tile + 1) * KTT * D_;
            kr0 = *(const bf16x8*)kp; kr1 = *(const bf16x8*)(kp + 8);
            const short* vp = vptr + (tile + 1) * KTT;
            vr0 = *(const bf16x8*)vp; vr1 = *(const bf16x8*)(vp + 8);
        }

        // ---- QK^T scores (log2 domain), 8 key-groups of 16 ----
        float sc[8][4];
        int am[8];
#pragma unroll
        for (int kt = 0; kt < 8; ++kt) am[kt] = amask[b * S_ + j0 + kt * 16 + lc];
        bool fullvis = (j0 + (KTT - 1) <= qb);   // wave-uniform
#pragma unroll
        for (int kt = 0; kt < 8; ++kt) {
            f32x4 s = {0.0f, 0.0f, 0.0f, 0.0f};
            bf16x8 k0 = *(const bf16x8*)&k_s[kt * 16 + lc][lg * 8];
            bf16x8 k1 = *(const bf16x8*)&k_s[kt * 16 + lc][32 + lg * 8];
            s = __builtin_amdgcn_mfma_f32_16x16x32_bf16(qfr[0], k0, s, 0, 0, 0);
            s = __builtin_amdgcn_mfma_f32_16x16x32_bf16(qfr[1], k1, s, 0, 0, 0);
            int jg = j0 + kt * 16 + lc;
            if (fullvis) {
#pragma unroll
                for (int reg = 0; reg < 4; ++reg) {
                    int qi = qb + lg * 4 + reg;
                    sc[kt][reg] = (am[kt] > 0) ? (s[reg] * scale2 - slope2 * (float)(qi - jg)) : -INFINITY;
                }
            } else {
#pragma unroll
                for (int reg = 0; reg < 4; ++reg) {
                    int qi = qb + lg * 4 + reg;
                    bool vis = (jg <= qi) && (am[kt] > 0);
                    sc[kt][reg] = vis ? (s[reg] * scale2 - slope2 * (float)(qi - jg)) : -INFINITY;
                }
            }
        }

        // ---- online softmax (log2 domain); sc overwritten with P in-place ----
#pragma unroll
        for (int reg = 0; reg < 4; ++reg) {
            float tm = fmaxf(fmaxf(fmaxf(sc[0][reg], sc[1][reg]), fmaxf(sc[2][reg], sc[3][reg])),
                             fmaxf(fmaxf(sc[4][reg], sc[5][reg]), fmaxf(sc[6][reg], sc[7][reg])));
#pragma unroll
            for (int msk = 1; msk <= 8; msk <<= 1) tm = fmaxf(tm, __shfl_xor(tm, msk));
            float mnew = fmaxf(mrow[reg], tm);
            fac[reg] = exp2f(mrow[reg] - mnew);
            mrow[reg] = mnew;
            float rs = 0.0f;
#pragma unroll
            for (int kt = 0; kt < 8; ++kt) {
                float p = exp2f(sc[kt][reg] - mnew);
                sc[kt][reg] = p;
                rs += p;
            }
#pragma unroll
            for (int msk = 1; msk <= 8; msk <<= 1) rs += __shfl_xor(rs, msk);
            lrow[reg] = lrow[reg] * fac[reg] + rs;
        }

        // ---- write P to per-wave LDS as bf16 pairs ----
        int parity = l & 1;
#pragma unroll
        for (int kt = 0; kt < 8; ++kt) {
#pragma unroll
            for (int rp = 0; rp < 4; rp += 2) {
                float s0 = sc[kt][rp];
                float s1 = sc[kt][rp + 1];
                float o0 = __shfl_xor(s0, 1);
                float o1 = __shfl_xor(s1, 1);
                float lo, hi; int reg;
                if (parity == 0) { lo = s0; hi = o0; reg = rp; }
                else             { lo = o1; hi = s1; reg = rp + 1; }
                unsigned pk = (unsigned)f2bf(lo) | ((unsigned)f2bf(hi) << 16);
                *(unsigned*)&p_s[w][lg * 4 + reg][kt * 16 + (lc & ~1)] = pk;
            }
        }
        __syncthreads();   // p_s ready

        // ---- PV accumulate (4 key-halves of 32) ----
#pragma unroll
        for (int db = 0; db < 4; ++db) {
#pragma unroll
            for (int reg = 0; reg < 4; ++reg) O[db][reg] *= fac[reg];
        }
#pragma unroll
        for (int kh = 0; kh < 4; ++kh) {
            bf16x8 a = *(const bf16x8*)&p_s[w][lc][kh * 32 + lg * 8];
#pragma unroll
            for (int db = 0; db < 4; ++db) {
                bf16x8 vb = *(const bf16x8*)&vT_s[db * 16 + lc][kh * 32 + lg * 8];
                O[db] = __builtin_amdgcn_mfma_f32_16x16x32_bf16(a, vb, O[db], 0, 0, 0);
            }
        }
    }

    // ================= peeled memory tile (10 retrieved events) =================
    {
        int sr = tid >> 3;              // 0..63
        int sc0 = (tid & 7) * 8;        // 0..56
        __syncthreads();   // PV readers of last real tile done
        short kv[8];
        if (sr < KT_) {
            const float* rp = ret + ((size_t)(b * KT_ + sr)) * D_ + h * DH_ + sc0;
            float4 a0 = *(const float4*)rp;
            float4 a1 = *(const float4*)(rp + 4);
            kv[0] = (short)f2bf(a0.x); kv[1] = (short)f2bf(a0.y);
            kv[2] = (short)f2bf(a0.z); kv[3] = (short)f2bf(a0.w);
            kv[4] = (short)f2bf(a1.x); kv[5] = (short)f2bf(a1.y);
            kv[6] = (short)f2bf(a1.z); kv[7] = (short)f2bf(a1.w);
        } else {
#pragma unroll
            for (int i = 0; i < 8; ++i) kv[i] = 0;
        }
        *(bf16x8*)&k_s[sr][sc0] = *(bf16x8*)&kv[0];
        __syncthreads();   // k_s ready
        short tv[8];
#pragma unroll
        for (int i = 0; i < 8; ++i) {
            int key = sc0 + i;
            tv[i] = (key < KT_) ? k_s[key][sr] : (short)0;
        }
        *(bf16x8*)&vT_s[sr][sc0] = *(bf16x8*)&tv[0];   // visible by p_s barrier below

        float scm[4];
        {
            f32x4 s = {0.0f, 0.0f, 0.0f, 0.0f};
            bf16x8 k0 = *(const bf16x8*)&k_s[lc][lg * 8];
            bf16x8 k1 = *(const bf16x8*)&k_s[lc][32 + lg * 8];
            s = __builtin_amdgcn_mfma_f32_16x16x32_bf16(qfr[0], k0, s, 0, 0, 0);
            s = __builtin_amdgcn_mfma_f32_16x16x32_bf16(qfr[1], k1, s, 0, 0, 0);
#pragma unroll
            for (int reg = 0; reg < 4; ++reg)
                scm[reg] = (lc < KT_) ? s[reg] * scale2 : -INFINITY;
        }
        float pm[4];
#pragma unroll
        for (int reg = 0; reg < 4; ++reg) {
            float tm = scm[reg];
#pragma unroll
            for (int msk = 1; msk <= 8; msk <<= 1) tm = fmaxf(tm, __shfl_xor(tm, msk));
            float mnew = fmaxf(mrow[reg], tm);
            fac[reg] = exp2f(mrow[reg] - mnew);
            mrow[reg] = mnew;
            float p = exp2f(scm[reg] - mnew);
            pm[reg] = p;
            float rs = p;
#pragma unroll
            for (int msk = 1; msk <= 8; msk <<= 1) rs += __shfl_xor(rs, msk);
            lrow[reg] = lrow[reg] * fac[reg] + rs;
        }
        int parity = l & 1;
#pragma unroll
        for (int kt = 0; kt < 2; ++kt) {
#pragma unroll
            for (int rp = 0; rp < 4; rp += 2) {
                float s0 = (kt == 1) ? 0.0f : pm[rp];
                float s1 = (kt == 1) ? 0.0f : pm[rp + 1];
                float o0 = __shfl_xor(s0, 1);
                float o1 = __shfl_xor(s1, 1);
                float lo, hi; int reg;
                if (parity == 0) { lo = s0; hi = o0; reg = rp; }
                else             { lo = o1; hi = s1; reg = rp + 1; }
                unsigned pk = (unsigned)f2bf(lo) | ((unsigned)f2bf(hi) << 16);
                *(unsigned*)&p_s[w][lg * 4 + reg][kt * 16 + (lc & ~1)] = pk;
            }
        }
        __syncthreads();   // p_s + vT_s ready
#pragma unroll
        for (int db = 0; db < 4; ++db) {
#pragma unroll
            for (int reg = 0; reg < 4; ++reg) O[db][reg] *= fac[reg];
        }
        {
            bf16x8 a = *(const bf16x8*)&p_s[w][lc][lg * 8];
#pragma unroll
            for (int db = 0; db < 4; ++db) {
                bf16x8 vb = *(const bf16x8*)&vT_s[db * 16 + lc][lg * 8];
                O[db] = __builtin_amdgcn_mfma_f32_16x16x32_bf16(a, vb, O[db], 0, 0, 0);
            }
        }
    }

    // ---- epilogue: write bf16 h/m splits of attention output ----
#pragma unroll
    for (int db = 0; db < 4; ++db) {
#pragma unroll
        for (int reg = 0; reg < 4; ++reg) {
            int qi = qb + lg * 4 + reg;
            size_t idx2 = ((size_t)(b * S_ + qi)) * D_ + h * DH_ + db * 16 + lc;
            float o = O[db][reg] / lrow[reg];
            unsigned short hb2 = f2bf(o);
            float hf = bf2f(hb2);
            unsigned short mb = f2bf(o - hf);
            AOh[idx2] = (short)hb2;
            AOm[idx2] = (short)mb;
        }
    }
}

// ---------------- launch ----------------
extern "C" void kernel_launch(void* const* d_in, const int* in_sizes, int n_in,
                              void* d_out, int out_size, void* d_ws, size_t ws_size,
                              hipStream_t stream)
{
    const float* X = (const float*)d_in[0];
    const int* amask = (const int*)d_in[1];
    const float* Wq = (const float*)d_in[2];
    const float* Wk = (const float*)d_in[3];
    const float* Wv = (const float*)d_in[4];
    const float* Wo = (const float*)d_in[5];
    float* out = (float*)d_out;

    char* p = (char*)d_ws;
    auto alloc = [&](size_t bytes) -> char* {
        char* r = p; p += (bytes + 255) & ~(size_t)255; return r;
    };
    double* sur = (double*)alloc((size_t)B_ * S_ * sizeof(double));
    float* kacc = (float*)alloc((size_t)2 * BS_ * D_ * sizeof(float));  // kf | kp1; reused by O split-K
    float* events = (float*)alloc((size_t)EVCAP_ * D_ * sizeof(float)); // reused as O partial2
    float* ret = (float*)alloc((size_t)B_ * KT_ * D_ * sizeof(float));
    float* sims = (float*)alloc((size_t)B_ * MEM_ * sizeof(float));
    int* seg_start = (int*)alloc((size_t)B_ * S_ * sizeof(int));
    int* seg_end = (int*)alloc((size_t)B_ * S_ * sizeof(int));
    int* scal = (int*)alloc(64);
    short* qbf = (short*)alloc((size_t)BS_ * D_ * sizeof(short));   // qbf|vbf span reused as O partial3
    short* vbf = (short*)alloc((size_t)BS_ * D_ * sizeof(short));
    short* vbfT = (short*)alloc((size_t)B_ * H_ * DH_ * S_ * sizeof(short));
    short* Xh = (short*)alloc((size_t)BS_ * D_ * sizeof(short));   // reused as AOh
    short* Xm = (short*)alloc((size_t)BS_ * D_ * sizeof(short));   // reused as AOm
    short* Xl = (short*)alloc((size_t)BS_ * D_ * sizeof(short));   // reused as kbf
    short* Wqh = (short*)alloc((size_t)D_ * D_ * sizeof(short));
    short* Wqm = (short*)alloc((size_t)D_ * D_ * sizeof(short));
    short* Wvh = (short*)alloc((size_t)D_ * D_ * sizeof(short));
    short* Wvm = (short*)alloc((size_t)D_ * D_ * sizeof(short));
    short* Woh = (short*)alloc((size_t)D_ * D_ * sizeof(short));
    short* Wom = (short*)alloc((size_t)D_ * D_ * sizeof(short));
    short* Wkh = (short*)alloc((size_t)D_ * D_ * sizeof(short));
    short* Wkm = (short*)alloc((size_t)D_ * D_ * sizeof(short));
    short* Wkl = (short*)alloc((size_t)D_ * D_ * sizeof(short));
    if ((size_t)(p - (char*)d_ws) > ws_size) return;  // insufficient workspace

    float* kf = kacc;
    float* kp1 = kacc + (size_t)BS_ * D_;
    short* kbf = Xl;

    // fused splits: X (4096 blocks) + 4 weights (4 x 1024 blocks)
    {
        SpArgs sa = {};
        sa.X = X; sa.Xh = Xh; sa.Xm = Xm; sa.Xl = Xl;
        sa.W[0] = Wq; sa.Wh[0] = Wqh; sa.Wm[0] = Wqm; sa.Wl[0] = nullptr;
        sa.W[1] = Wk; sa.Wh[1] = Wkh; sa.Wm[1] = Wkm; sa.Wl[1] = Wkl;
        sa.W[2] = Wv; sa.Wh[2] = Wvh; sa.Wm[2] = Wvm; sa.Wl[2] = nullptr;
        sa.W[3] = Wo; sa.Wh[3] = Woh; sa.Wm[3] = Wom; sa.Wl[3] = nullptr;
        sa.nx4 = BS_ * D_ / 4;
        split_all_kernel<<<4096 + 4096, 256, 0, stream>>>(sa);
    }

    // Fused QV + K(split-K 2) GEMM: 256 blocks x 512 thr (256² tiles, 4-deep pipeline).
    {
        G8Args ga = {};
        ga.A[0][0] = Xm;  ga.A[0][1] = Xh;  ga.A[0][2] = Xh;
        ga.B[0][0] = Wqh; ga.B[0][1] = Wqm; ga.B[0][2] = Wqh;
        ga.outb[0] = qbf;
        ga.A[1][0] = Xm;  ga.A[1][1] = Xh;  ga.A[1][2] = Xh;
        ga.B[1][0] = Wvh; ga.B[1][1] = Wvm; ga.B[1][2] = Wvh;
        ga.outb[1] = vbf;
        ga.A[2][0] = Xh;  ga.A[2][1] = Xm;  ga.A[2][2] = Xm;
        ga.B[2][0] = Wkm; ga.B[2][1] = Wkh; ga.B[2][2] = Wkm;
        ga.outf[2] = kf;
        ga.A[3][0] = Xh;  ga.A[3][1] = Xl;  ga.A[3][2] = Xh;
        ga.B[3][0] = Wkl; ga.B[3][1] = Wkh; ga.B[3][2] = Wkh;
        ga.outf[3] = kp1;
        ga.gsbase[0] = 0; ga.gsbase[1] = 0; ga.gsbase[2] = 0; ga.gsbase[3] = 0;
        ga.nt = 96;
        gemm8<<<256, 512, 0, stream>>>(ga);
    }
    // fused: V transpose (1024 blocks) + K split-K add (4096 blocks)
    fixup_kernel<<<1024 + BS_ * D_ / 4 / 256, 256, 0, stream>>>(vbf, vbfT, kf, kp1, kbf);

    surprise_kernel<<<dim3(S_, B_), 256, 0, stream>>>(kf, sur);
    boundary2_kernel<<<1, 256, 0, stream>>>(sur, seg_start, seg_end, scal);
    seg_means_kernel<<<dim3(S_, B_), 256, 0, stream>>>(kf, events, seg_start, seg_end, scal);
    sims_kernel<<<dim3(MEM_, B_), 256, 0, stream>>>(events, kf, sims, scal);
    topk_kernel<<<B_, 256, 0, stream>>>(events, sims, ret, scal);

    attn_mfma_kernel<<<512, 512, 0, stream>>>(qbf, kbf, vbfT, ret, amask, Xh, Xm);

    // O GEMM: A = attention-output splits (AOm,AOh,AOh), split-K=4 -> 256 blocks
    {
        float* p2 = events;
        float* p3 = (float*)qbf;   // qbf|vbf span (contiguous 16 MB) — dead after attn
        G8Args ga = {};
        for (int g = 0; g < 4; ++g) {
            ga.A[g][0] = Xm;  ga.A[g][1] = Xh;  ga.A[g][2] = Xh;
            ga.B[g][0] = Woh; ga.B[g][1] = Wom; ga.B[g][2] = Woh;
            ga.gsbase[g] = g * 24;
        }
        ga.outf[0] = kf; ga.outf[1] = kp1; ga.outf[2] = p2; ga.outf[3] = p3;
        ga.nt = 24;
        gemm8<<<256, 512, 0, stream>>>(ga);
        addo4_kernel<<<BS_ * D_ / 4 / 256, 256, 0, stream>>>(kf, kp1, p2, p3, out);
    }
}

// Round 19
// 342.674 us; speedup vs baseline: 1.2589x; 1.2589x over previous
//
#include <hip/hip_runtime.h>
#include <math.h>

#define B_ 2
#define S_ 2048
#define H_ 16
#define DH_ 64
#define D_ 1024
#define MEM_ 1000
#define KT_ 10
#define THRESH_ 0.5
#define BS_ (B_ * S_)
#define EVCAP_ (2 * S_)   // max possible events (<= S per sample)

typedef float f32x4 __attribute__((ext_vector_type(4)));
typedef short bf16x8 __attribute__((ext_vector_type(8)));
typedef short s16x4 __attribute__((ext_vector_type(4)));

__device__ inline unsigned short f2bf(float f) {
    union { float f; unsigned u; } v; v.f = f;
    unsigned u = v.u;
    unsigned r = (u + 0x7FFFu + ((u >> 16) & 1u)) >> 16;  // RNE
    return (unsigned short)r;
}
__device__ inline float bf2f(unsigned short h) {
    union { unsigned u; float f; } v; v.u = ((unsigned)h) << 16; return v.f;
}

// async global->LDS, 16B per lane; LDS dest = wave-uniform base + lane*16
__device__ __forceinline__ void gload16(const short* gp, const short* lp) {
    __builtin_amdgcn_global_load_lds(
        (__attribute__((address_space(1))) void*)(unsigned long long)gp,
        (__attribute__((address_space(3))) void*)(unsigned)(unsigned long long)lp,
        16, 0, 0);
}

// ---------------- fused input split: X (h,m,l) + 4 weights in ONE dispatch ----
struct SpArgs {
    const float* X;
    short *Xh, *Xm, *Xl;
    const float* W[4];          // Wq, Wk, Wv, Wo
    short *Wh[4], *Wm[4], *Wl[4];  // Wl null -> skip
    int nx4;                    // X f32x4 count (4096 blocks worth)
};
__global__ __launch_bounds__(256) void split_all_kernel(SpArgs sa)
{
    int bid = blockIdx.x;
    const float* src; short *ph, *pm, *pl; int i;
    if (bid < 4096) {               // X section
        i = bid * 256 + threadIdx.x;
        if (i >= sa.nx4) return;
        src = sa.X; ph = sa.Xh; pm = sa.Xm; pl = sa.Xl;
    } else {                        // weight section: 1024 blocks each
        int wb = bid - 4096;
        int y = wb >> 10;
        i = (wb & 1023) * 256 + threadIdx.x;
        src = sa.W[y]; ph = sa.Wh[y]; pm = sa.Wm[y]; pl = sa.Wl[y];
    }
    float4 x = ((const float4*)src)[i];
    float xs[4] = {x.x, x.y, x.z, x.w};
    s16x4 hv, mv, lv;
    bool wl = (pl != nullptr);
#pragma unroll
    for (int j = 0; j < 4; ++j) {
        unsigned short hb = f2bf(xs[j]);
        float hf = bf2f(hb);
        float r1 = xs[j] - hf;            // exact in f32
        unsigned short mb = f2bf(r1);
        hv[j] = (short)hb; mv[j] = (short)mb;
        if (wl) {
            float mf = bf2f(mb);
            lv[j] = (short)f2bf(r1 - mf); // exact residual, rounded
        }
    }
    ((s16x4*)ph)[i] = hv;
    ((s16x4*)pm)[i] = mv;
    if (wl) ((s16x4*)pl)[i] = lv;
}

// ---------------- 256x256 single-phase split-precision bf16 MFMA GEMM ----------
// BK=32, triple-buffered LDS (96 KiB), counted vmcnt(4). Per tile:
// stage(t+2) issued FIRST, then 12 ds_read_b128 + 32 MFMA + vmcnt + ONE barrier.
struct G8Args {
    const short* A[4][3];   // per-group A term pointers (term id = gs>>5)
    const short* B[4][3];
    short* outb[4];         // bf16 output (or null)
    float* outf[4];         // f32 output (used when outb[g]==null)
    int gsbase[4];          // global K-step (32-wide) base per group
    int nt;                 // K-tiles per block (>= 2)
};

__global__ __launch_bounds__(512, 2) void gemm8(G8Args ga)
{
    __shared__ __align__(16) short Abuf[3][2][4096];   // [buf][half(128 rows)][packed 128x32]
    __shared__ __align__(16) short Bbuf[3][2][4096];

    int wg = blockIdx.x;
    int lin = (wg & 7) * 32 + (wg >> 3);   // XCD-clustered (256 % 8 == 0 -> bijective)
    int jb = lin >> 4;                     // (g, bcol): 2 per XCD -> B panels L2-resident
    int by = lin & 15;                     // row panel 0..15
    int g = jb >> 2;
    int bcol = jb & 3;

    int tid = threadIdx.x;
    int w = tid >> 6, l = tid & 63;
    int wm = w >> 2, wn = w & 3;           // wave grid 2M x 4N
    int lg = l >> 4, lc = l & 15;

    const short* A0 = ga.A[g][0]; const short* A1 = ga.A[g][1]; const short* A2 = ga.A[g][2];
    const short* B0 = ga.B[g][0]; const short* B1 = ga.B[g][1]; const short* B2 = ga.B[g][2];
    const int gs0 = ga.gsbase[g];
    const int NT = ga.nt;

    const int u = tid;
    const int vswz = (u & 7) ^ ((u >> 3) & 7);
    const int srow = 2 * (u >> 3) + (vswz >> 2);     // 0..127 within half
    const int skcol = (vswz & 3) * 8;                // shorts
    const size_t abase = (size_t)(by * 256) * D_ + skcol;
    const size_t bbase = (size_t)(bcol * 256) * D_ + skcol;
    const int dst0 = w * 512;                        // wave-uniform LDS short offset

    auto STAGE_A = [&](int ts, int d) {
        int tt = ts >> 5; int k0 = (ts & 31) << 5;
        const short* At = (tt == 0) ? A0 : ((tt == 1) ? A1 : A2);
        const short* Ab = At + abase + k0;
#pragma unroll
        for (int h = 0; h < 2; ++h)
            gload16(Ab + (size_t)(h * 128 + srow) * D_, &Abuf[d][h][dst0]);
    };
    auto STAGE_B = [&](int ts, int d) {
        int tt = ts >> 5; int k0 = (ts & 31) << 5;
        const short* Bt = (tt == 0) ? B0 : ((tt == 1) ? B1 : B2);
        const short* Bb = Bt + bbase + k0;
#pragma unroll
        for (int h = 0; h < 2; ++h)
            gload16(Bb + (size_t)(h * 128 + srow) * D_, &Bbuf[d][h][dst0]);
    };

    f32x4 acc[8][4] = {};
    const int psa = (((((lc & 1) << 2) | lg)) ^ ((lc >> 1) & 7)) * 8;
    const int rbase = (lc >> 1) * 64;

    // prologue: stage tiles 0 and 1
    STAGE_A(gs0, 0); STAGE_B(gs0, 0);
    STAGE_A(gs0 + 1, 1); STAGE_B(gs0 + 1, 1);
    asm volatile("s_waitcnt vmcnt(4)" ::: "memory");   // tile 0 landed; tile 1 in flight
    asm volatile("s_barrier" ::: "memory");
    __builtin_amdgcn_sched_barrier(0);

    int d = 0, ds = 2;
    for (int t = 0; t < NT; ++t) {
        // stage t+2 FIRST: enters memory system earlier; buffer ds held tile t-1
        // whose readers completed before the previous barrier -> safe.
        if (t + 2 < NT) { STAGE_A(gs0 + t + 2, ds); STAGE_B(gs0 + t + 2, ds); }
        const short* Ab0 = &Abuf[d][wm][rbase + psa];
        const short* Bb0 = &Bbuf[d][wn >> 1][(wn & 1) * 2048 + rbase + psa];
        bf16x8 av[8], bv[4];
#pragma unroll
        for (int nf = 0; nf < 4; ++nf) bv[nf] = *(const bf16x8*)&Bb0[nf * 512];
#pragma unroll
        for (int mf = 0; mf < 8; ++mf) av[mf] = *(const bf16x8*)&Ab0[mf * 512];
        __builtin_amdgcn_s_setprio(1);
#pragma unroll
        for (int mf = 0; mf < 8; ++mf)
#pragma unroll
            for (int nf = 0; nf < 4; ++nf)
                acc[mf][nf] = __builtin_amdgcn_mfma_f32_16x16x32_bf16(av[mf], bv[nf], acc[mf][nf], 0, 0, 0);
        __builtin_amdgcn_s_setprio(0);
        if (t + 2 < NT) asm volatile("s_waitcnt vmcnt(4)" ::: "memory");   // t+1 landed, t+2 in flight
        else            asm volatile("s_waitcnt vmcnt(0)" ::: "memory");   // drain tail
        asm volatile("s_barrier" ::: "memory");
        __builtin_amdgcn_sched_barrier(0);
        d = (d == 2) ? 0 : d + 1;
        ds = (ds == 2) ? 0 : ds + 1;
    }

    // epilogue
    short* ob = ga.outb[g];
    if (ob) {
#pragma unroll
        for (int mf = 0; mf < 8; ++mf)
#pragma unroll
            for (int nf = 0; nf < 4; ++nf)
#pragma unroll
                for (int reg = 0; reg < 4; ++reg) {
                    int row = by * 256 + wm * 128 + mf * 16 + lg * 4 + reg;
                    int col = bcol * 256 + wn * 64 + nf * 16 + lc;
                    ob[(size_t)row * D_ + col] = (short)f2bf(acc[mf][nf][reg]);
                }
    } else {
        float* of = ga.outf[g];
#pragma unroll
        for (int mf = 0; mf < 8; ++mf)
#pragma unroll
            for (int nf = 0; nf < 4; ++nf)
#pragma unroll
                for (int reg = 0; reg < 4; ++reg) {
                    int row = by * 256 + wm * 128 + mf * 16 + lg * 4 + reg;
                    int col = bcol * 256 + wn * 64 + nf * 16 + lc;
                    of[(size_t)row * D_ + col] = acc[mf][nf][reg];
                }
    }
}

// ---------------- fused post-QVK: V transpose + K split-K add (one dispatch) ----
__global__ __launch_bounds__(256) void fixup_kernel(const short* __restrict__ vbf,
                                                    short* __restrict__ vbfT,
                                                    float* __restrict__ kf,
                                                    const float* __restrict__ kp1,
                                                    short* __restrict__ kbf)
{
    int bid = blockIdx.x;
    int tid = threadIdx.x;
    if (bid < 1024) {
        __shared__ short st[64][70];
        int t = bid;
        int s0 = (t & 31) * 64;
        int h = (t >> 5) & 15;
        int b = t >> 9;
        int r = tid >> 2, cb = (tid & 3) * 16;
        const short* src = vbf + (size_t)(b * S_ + s0 + r) * D_ + h * DH_ + cb;
        *(bf16x8*)&st[r][cb] = *(const bf16x8*)src;
        *(bf16x8*)&st[r][cb + 8] = *(const bf16x8*)(src + 8);
        __syncthreads();
        int c = tid >> 2, sb = (tid & 3) * 16;
        short tmp[16];
#pragma unroll
        for (int i = 0; i < 16; ++i) tmp[i] = st[sb + i][c];
        short* dst = vbfT + ((size_t)(b * H_ + h) * DH_ + c) * S_ + s0 + sb;
        *(bf16x8*)dst = *(bf16x8*)&tmp[0];
        *(bf16x8*)(dst + 8) = *(bf16x8*)&tmp[8];
    } else {
        size_t i = (size_t)(bid - 1024) * 256 + tid;
        float4 a = ((const float4*)kf)[i];
        float4 b = ((const float4*)kp1)[i];
        float4 s = {a.x + b.x, a.y + b.y, a.z + b.z, a.w + b.w};
        ((float4*)kf)[i] = s;
        s16x4 o;
        o[0] = (short)f2bf(s.x); o[1] = (short)f2bf(s.y);
        o[2] = (short)f2bf(s.z); o[3] = (short)f2bf(s.w);
        ((s16x4*)kbf)[i] = o;
    }
}

__global__ __launch_bounds__(256) void addo4_kernel(const float* __restrict__ p0,
                                                    const float* __restrict__ p1,
                                                    const float* __restrict__ p2,
                                                    const float* __restrict__ p3,
                                                    float* __restrict__ out)
{
    size_t i = (size_t)blockIdx.x * 256 + threadIdx.x;
    float4 a = ((const float4*)p0)[i];
    float4 b = ((const float4*)p1)[i];
    float4 c = ((const float4*)p2)[i];
    float4 d = ((const float4*)p3)[i];
    float4 s = {((a.x + b.x) + c.x) + d.x, ((a.y + b.y) + c.y) + d.y,
                ((a.z + b.z) + c.z) + d.z, ((a.w + b.w) + c.w) + d.w};
    ((float4*)out)[i] = s;
}

// ---------------- surprise (both batches): sur[b][t] = ||kf[t]-kf[t-1]|| ----------
__global__ __launch_bounds__(256) void surprise_kernel(const float* __restrict__ kf,
                                                       double* __restrict__ sur)
{
    int t = blockIdx.x;
    int b = blockIdx.y;
    if (t == 0) { if (threadIdx.x == 0) sur[(size_t)b * S_] = 0.0; return; }
    const float* kfb = kf + (size_t)b * S_ * D_;
    __shared__ double red[256];
    double acc = 0.0;
    for (int d = threadIdx.x; d < D_; d += 256) {
        double df = (double)kfb[(size_t)t * D_ + d] - (double)kfb[(size_t)(t - 1) * D_ + d];
        acc += df * df;
    }
    red[threadIdx.x] = acc;
    __syncthreads();
    for (int s = 128; s > 0; s >>= 1) {
        if (threadIdx.x < s) red[threadIdx.x] += red[threadIdx.x + s];
        __syncthreads();
    }
    if (threadIdx.x == 0) sur[(size_t)b * S_ + t] = sqrt(red[0]);
}

// ---------------- boundaries BOTH batches (single block; batch loop preserves
// the reference's sequential FIFO semantics). scal: [4+b]=nseg_b, [6+b]=evbase_b.
__global__ __launch_bounds__(256) void boundary2_kernel(const double* __restrict__ sur,
                                                        int* __restrict__ seg_start,
                                                        int* __restrict__ seg_end,
                                                        int* __restrict__ scal)
{
    __shared__ double lsur[S_];
    __shared__ double red[256];
    __shared__ double sh_mean, sh_thr;
    __shared__ int cnt[256];
    int tid = threadIdx.x;
    int running = 0;
    for (int b = 0; b < B_; ++b) {
        __syncthreads();
        for (int t = tid; t < S_; t += 256) lsur[t] = sur[(size_t)b * S_ + t];
        __syncthreads();
        double a = 0.0;
        for (int t = tid; t < S_; t += 256) a += lsur[t];
        red[tid] = a;
        __syncthreads();
        for (int s = 128; s > 0; s >>= 1) {
            if (tid < s) red[tid] += red[tid + s];
            __syncthreads();
        }
        if (tid == 0) sh_mean = red[0] / (double)S_;
        __syncthreads();
        double mean = sh_mean;
        a = 0.0;
        for (int t = tid; t < S_; t += 256) { double d = lsur[t] - mean; a += d * d; }
        red[tid] = a;
        __syncthreads();
        for (int s = 128; s > 0; s >>= 1) {
            if (tid < s) red[tid] += red[tid + s];
            __syncthreads();
        }
        if (tid == 0) sh_thr = mean + THRESH_ * sqrt(red[0] / (double)(S_ - 1));
        __syncthreads();
        double thr = sh_thr;
        bool flg[8];
        int c = 0;
#pragma unroll
        for (int j = 0; j < 8; ++j) {
            int t = tid * 8 + j;
            flg[j] = (lsur[t] > thr) || (t == S_ - 1);
            c += flg[j] ? 1 : 0;
        }
        cnt[tid] = c;
        __syncthreads();
        for (int off = 1; off < 256; off <<= 1) {   // Hillis-Steele inclusive scan
            int v = cnt[tid];
            int add = (tid >= off) ? cnt[tid - off] : 0;
            __syncthreads();
            cnt[tid] = v + add;
            __syncthreads();
        }
        int r = (tid == 0) ? 0 : cnt[tid - 1];
        int* se = seg_end + b * S_;
        int* ss = seg_start + b * S_;
#pragma unroll
        for (int j = 0; j < 8; ++j) {
            if (flg[j]) { se[r] = tid * 8 + j; ++r; }
        }
        __syncthreads();
        int n = cnt[255];
        for (int i = tid; i < n; i += 256)
            ss[i] = (i == 0) ? 0 : se[i - 1] + 1;
        if (tid == 0) {
            scal[4 + b] = n;        // nseg_b
            scal[6 + b] = running;  // evbase_b
        }
        running += n;
        __syncthreads();
    }
}

// ---------------- segment means BOTH batches -> append events ----------------
__global__ __launch_bounds__(256) void seg_means_kernel(const float* __restrict__ kf,
                                                        float* __restrict__ events,
                                                        const int* __restrict__ seg_start,
                                                        const int* __restrict__ seg_end,
                                                        const int* __restrict__ scal)
{
    int g = blockIdx.x;
    int b = blockIdx.y;
    if (g >= scal[4 + b]) return;
    const float* kfb = kf + (size_t)b * S_ * D_;
    int s = seg_start[b * S_ + g], e = seg_end[b * S_ + g];
    double inv = 1.0 / (double)(e - s + 1);
    size_t obase = (size_t)(scal[6 + b] + g) * D_;
    for (int d = threadIdx.x; d < D_; d += 256) {
        double acc = 0.0;
        for (int r = s; r <= e; ++r) acc += (double)kfb[(size_t)r * D_ + d];
        events[obase + d] = (float)(acc * inv);
    }
}

// ---------------- cosine sims BOTH batches vs each batch's last key ----------
__global__ __launch_bounds__(256) void sims_kernel(const float* __restrict__ events,
                                                   const float* __restrict__ kf,
                                                   float* __restrict__ sims,
                                                   const int* __restrict__ scal)
{
    int e = blockIdx.x;
    int b = blockIdx.y;
    int total = scal[6 + b] + scal[4 + b];   // events appended through batch b
    int w = total < MEM_ ? total : MEM_;
    float* sb = sims + b * MEM_;
    if (e >= w) { if (threadIdx.x == 0) sb[e] = -INFINITY; return; }
    int wstart = total - w;
    const float* ev = events + (size_t)(wstart + e) * D_;
    const float* q = kf + ((size_t)(b * S_ + S_ - 1)) * D_;
    __shared__ double r1[256], r2[256], r3[256];
    int tid = threadIdx.x;
    double dot = 0.0, n2 = 0.0, q2 = 0.0;
    for (int d = tid; d < D_; d += 256) {
        double ed = ev[d], qd = q[d];
        dot += ed * qd; n2 += ed * ed; q2 += qd * qd;
    }
    r1[tid] = dot; r2[tid] = n2; r3[tid] = q2;
    __syncthreads();
    for (int s = 128; s > 0; s >>= 1) {
        if (tid < s) { r1[tid] += r1[tid + s]; r2[tid] += r2[tid + s]; r3[tid] += r3[tid + s]; }
        __syncthreads();
    }
    if (tid == 0) {
        double mn = sqrt(r2[0]); if (mn < 1e-8) mn = 1e-8;
        double qn = sqrt(r3[0]); if (qn < 1e-8) qn = 1e-8;
        sb[e] = (float)(r1[0] / (mn * qn));
    }
}

// ---------------- top-KT BOTH batches (block b) + gather ----------------
__global__ __launch_bounds__(256) void topk_kernel(const float* __restrict__ events,
                                                   float* __restrict__ sims,
                                                   float* __restrict__ ret,
                                                   const int* __restrict__ scal)
{
    int b = blockIdx.x;
    int total = scal[6 + b] + scal[4 + b];
    int w = total < MEM_ ? total : MEM_;
    int wstart = total - w;
    float* sb = sims + b * MEM_;
    float* retb = ret + (size_t)b * KT_ * D_;
    __shared__ float bv[256];
    __shared__ int bidx[256];
    __shared__ int chosen;
    int tid = threadIdx.x;
    for (int r = 0; r < KT_; ++r) {
        float best = -INFINITY;
        int bi = 0x7fffffff;
        for (int e = tid; e < w; e += 256) {
            float v = sb[e];
            if (v > best || (v == best && e < bi)) { best = v; bi = e; }
        }
        bv[tid] = best; bidx[tid] = bi;
        __syncthreads();
        for (int s = 128; s > 0; s >>= 1) {
            if (tid < s) {
                if (bv[tid + s] > bv[tid] || (bv[tid + s] == bv[tid] && bidx[tid + s] < bidx[tid])) {
                    bv[tid] = bv[tid + s]; bidx[tid] = bidx[tid + s];
                }
            }
            __syncthreads();
        }
        if (tid == 0) {
            chosen = (r < w) ? bidx[0] : -1;
            if (chosen >= 0) sb[chosen] = -INFINITY;
        }
        __syncthreads();
        int c = chosen;
        if (c >= 0) {
            const float* ev = events + (size_t)(wstart + c) * D_;
            for (int d = tid; d < D_; d += 256) retb[(size_t)r * D_ + d] = ev[d];
        } else {
            for (int d = tid; d < D_; d += 256) retb[(size_t)r * D_ + d] = 0.0f;
        }
        __syncthreads();
    }
}

// ---------------- attention: bf16 MFMA flash, QTT=128, KTT=128, peeled memtile ----
#define QTT 128
#define KTT 128
__global__ __launch_bounds__(512, 4) void attn_mfma_kernel(const short* __restrict__ qbf,
                                                           const short* __restrict__ kbf,
                                                           const short* __restrict__ vbfT,
                                                           const float* __restrict__ ret,
                                                           const int* __restrict__ amask,
                                                           short* __restrict__ AOh,
                                                           short* __restrict__ AOm)
{
    __shared__ __align__(16) short k_s[KTT][72];       // [key][d]   (row 144B)
    __shared__ __align__(16) short vT_s[DH_][136];     // [d][key]   (row 272B)
    __shared__ __align__(16) short p_s[8][16][136];    // per-wave [q][key]

    const float LOG2E = 1.4426950408889634f;
    int bid = blockIdx.x;                    // 0..511
    int xcd = bid & 7;
    int idx = bid >> 3;                      // 0..63
    int qtslot = idx >> 2;                   // 0..15
    int hbL = idx & 3;                       // 0..3
    int qt = (qtslot < 8) ? (15 - qtslot) : (qtslot - 8);
    int hb = xcd * 4 + hbL;                  // 0..31
    int h = hb & 15, b = hb >> 4;
    int q0 = qt * QTT;

    int tid = threadIdx.x;
    int w = tid >> 6, l = tid & 63;          // 8 waves
    int lg = l >> 4, lc = l & 15;
    int qb = q0 + w * 16;                    // this wave's 16 queries
    float scale2 = 0.125f * LOG2E;
    float slope2 = exp2f(-0.5f * (float)(h + 1)) * LOG2E;

    bf16x8 qfr[2];
#pragma unroll
    for (int half = 0; half < 2; ++half)
        qfr[half] = *(const bf16x8*)(qbf + ((size_t)(b * S_ + qb + lc)) * D_ + h * DH_ + half * 32 + lg * 8);

    float mrow[4], lrow[4], fac[4];
#pragma unroll
    for (int r = 0; r < 4; ++r) { mrow[r] = -INFINITY; lrow[r] = 0.0f; }
    f32x4 O[4] = {};

    // main-loop staging indices
    int skr = tid >> 2;             // K stage: key row 0..127
    int skc = (tid & 3) * 16;       // K stage: d col base (16 shorts)
    int sdv = tid >> 3;             // V stage: d row 0..63
    int skk = (tid & 7) * 16;       // V stage: key col base (16 shorts)

    const short* kptr = kbf + ((size_t)(b * S_ + skr)) * D_ + h * DH_ + skc;
    const short* vptr = vbfT + ((size_t)(b * H_ + h) * DH_ + sdv) * S_ + skk;

    int ntiles = qt + 1;            // K-tiles of 128 keys
    bf16x8 kr0 = *(const bf16x8*)kptr, kr1 = *(const bf16x8*)(kptr + 8);
    bf16x8 vr0 = *(const bf16x8*)vptr, vr1 = *(const bf16x8*)(vptr + 8);

    for (int tile = 0; tile < ntiles; ++tile) {
        int j0 = tile * KTT;
        __syncthreads();   // all readers of previous tile done
        *(bf16x8*)&k_s[skr][skc] = kr0;
        *(bf16x8*)&k_s[skr][skc + 8] = kr1;
        *(bf16x8*)&vT_s[sdv][skk] = vr0;
        *(bf16x8*)&vT_s[sdv][skk + 8] = vr1;
        __syncthreads();   // tile visible
        if (tile + 1 < ntiles) {   // prefetch next tile (latency hidden under compute)
            const short* kp = kptr + (size_t)(tile + 1) * KTT * D_;
            kr0 = *(const bf16x8*)kp; kr1 = *(const bf16x8*)(kp + 8);
            const short* vp = vptr + (tile + 1) * KTT;
            vr0 = *(const bf16x8*)vp; vr1 = *(const bf16x8*)(vp + 8);
        }

        // ---- QK^T scores (log2 domain), 8 key-groups of 16 ----
        float sc[8][4];
        int am[8];
#pragma unroll
        for (int kt = 0; kt < 8; ++kt) am[kt] = amask[b * S_ + j0 + kt * 16 + lc];
        bool fullvis = (j0 + (KTT - 1) <= qb);   // wave-uniform
#pragma unroll
        for (int kt = 0; kt < 8; ++kt) {
            f32x4 s = {0.0f, 0.0f, 0.0f, 0.0f};
            bf16x8 k0 = *(const bf16x8*)&k_s[kt * 16 + lc][lg * 8];
            bf16x8 k1 = *(const bf16x8*)&k_s[kt * 16 + lc][32 + lg * 8];
            s = __builtin_amdgcn_mfma_f32_16x16x32_bf16(qfr[0], k0, s, 0, 0, 0);
            s = __builtin_amdgcn_mfma_f32_16x16x32_bf16(qfr[1], k1, s, 0, 0, 0);
            int jg = j0 + kt * 16 + lc;
            if (fullvis) {
#pragma unroll
                for (int reg = 0; reg < 4; ++reg) {
                    int qi = qb + lg * 4 + reg;
                    sc[kt][reg] = (am[kt] > 0) ? (s[reg] * scale2 - slope2 * (float)(qi - jg)) : -INFINITY;
                }
            } else {
#pragma unroll
                for (int reg = 0; reg < 4; ++reg) {
                    int qi = qb + lg * 4 + reg;
                    bool vis = (jg <= qi) && (am[kt] > 0);
                    sc[kt][reg] = vis ? (s[reg] * scale2 - slope2 * (float)(qi - jg)) : -INFINITY;
                }
            }
        }

        // ---- online softmax (log2 domain); sc overwritten with P in-place ----
#pragma unroll
        for (int reg = 0; reg < 4; ++reg) {
            float tm = fmaxf(fmaxf(fmaxf(sc[0][reg], sc[1][reg]), fmaxf(sc[2][reg], sc[3][reg])),
                             fmaxf(fmaxf(sc[4][reg], sc[5][reg]), fmaxf(sc[6][reg], sc[7][reg])));
#pragma unroll
            for (int msk = 1; msk <= 8; msk <<= 1) tm = fmaxf(tm, __shfl_xor(tm, msk));
            float mnew = fmaxf(mrow[reg], tm);
            fac[reg] = exp2f(mrow[reg] - mnew);
            mrow[reg] = mnew;
            float rs = 0.0f;
#pragma unroll
            for (int kt = 0; kt < 8; ++kt) {
                float p = exp2f(sc[kt][reg] - mnew);
                sc[kt][reg] = p;
                rs += p;
            }
#pragma unroll
            for (int msk = 1; msk <= 8; msk <<= 1) rs += __shfl_xor(rs, msk);
            lrow[reg] = lrow[reg] * fac[reg] + rs;
        }

        // ---- write P to per-wave LDS as bf16 pairs ----
        int parity = l & 1;
#pragma unroll
        for (int kt = 0; kt < 8; ++kt) {
#pragma unroll
            for (int rp = 0; rp < 4; rp += 2) {
                float s0 = sc[kt][rp];
                float s1 = sc[kt][rp + 1];
                float o0 = __shfl_xor(s0, 1);
                float o1 = __shfl_xor(s1, 1);
                float lo, hi; int reg;
                if (parity == 0) { lo = s0; hi = o0; reg = rp; }
                else             { lo = o1; hi = s1; reg = rp + 1; }
                unsigned pk = (unsigned)f2bf(lo) | ((unsigned)f2bf(hi) << 16);
                *(unsigned*)&p_s[w][lg * 4 + reg][kt * 16 + (lc & ~1)] = pk;
            }
        }
        __syncthreads();   // p_s ready

        // ---- PV accumulate (4 key-halves of 32) ----
#pragma unroll
        for (int db = 0; db < 4; ++db) {
#pragma unroll
            for (int reg = 0; reg < 4; ++reg) O[db][reg] *= fac[reg];
        }
#pragma unroll
        for (int kh = 0; kh < 4; ++kh) {
            bf16x8 a = *(const bf16x8*)&p_s[w][lc][kh * 32 + lg * 8];
#pragma unroll
            for (int db = 0; db < 4; ++db) {
                bf16x8 vb = *(const bf16x8*)&vT_s[db * 16 + lc][kh * 32 + lg * 8];
                O[db] = __builtin_amdgcn_mfma_f32_16x16x32_bf16(a, vb, O[db], 0, 0, 0);
            }
        }
    }

    // ================= peeled memory tile (10 retrieved events) =================
    {
        int sr = tid >> 3;              // 0..63
        int sc0 = (tid & 7) * 8;        // 0..56
        __syncthreads();   // PV readers of last real tile done
        short kv[8];
        if (sr < KT_) {
            const float* rp = ret + ((size_t)(b * KT_ + sr)) * D_ + h * DH_ + sc0;
            float4 a0 = *(const float4*)rp;
            float4 a1 = *(const float4*)(rp + 4);
            kv[0] = (short)f2bf(a0.x); kv[1] = (short)f2bf(a0.y);
            kv[2] = (short)f2bf(a0.z); kv[3] = (short)f2bf(a0.w);
            kv[4] = (short)f2bf(a1.x); kv[5] = (short)f2bf(a1.y);
            kv[6] = (short)f2bf(a1.z); kv[7] = (short)f2bf(a1.w);
        } else {
#pragma unroll
            for (int i = 0; i < 8; ++i) kv[i] = 0;
        }
        *(bf16x8*)&k_s[sr][sc0] = *(bf16x8*)&kv[0];
        __syncthreads();   // k_s ready
        short tv[8];
#pragma unroll
        for (int i = 0; i < 8; ++i) {
            int key = sc0 + i;
            tv[i] = (key < KT_) ? k_s[key][sr] : (short)0;
        }
        *(bf16x8*)&vT_s[sr][sc0] = *(bf16x8*)&tv[0];   // visible by p_s barrier below

        float scm[4];
        {
            f32x4 s = {0.0f, 0.0f, 0.0f, 0.0f};
            bf16x8 k0 = *(const bf16x8*)&k_s[lc][lg * 8];
            bf16x8 k1 = *(const bf16x8*)&k_s[lc][32 + lg * 8];
            s = __builtin_amdgcn_mfma_f32_16x16x32_bf16(qfr[0], k0, s, 0, 0, 0);
            s = __builtin_amdgcn_mfma_f32_16x16x32_bf16(qfr[1], k1, s, 0, 0, 0);
#pragma unroll
            for (int reg = 0; reg < 4; ++reg)
                scm[reg] = (lc < KT_) ? s[reg] * scale2 : -INFINITY;
        }
        float pm[4];
#pragma unroll
        for (int reg = 0; reg < 4; ++reg) {
            float tm = scm[reg];
#pragma unroll
            for (int msk = 1; msk <= 8; msk <<= 1) tm = fmaxf(tm, __shfl_xor(tm, msk));
            float mnew = fmaxf(mrow[reg], tm);
            fac[reg] = exp2f(mrow[reg] - mnew);
            mrow[reg] = mnew;
            float p = exp2f(scm[reg] - mnew);
            pm[reg] = p;
            float rs = p;
#pragma unroll
            for (int msk = 1; msk <= 8; msk <<= 1) rs += __shfl_xor(rs, msk);
            lrow[reg] = lrow[reg] * fac[reg] + rs;
        }
        int parity = l & 1;
#pragma unroll
        for (int kt = 0; kt < 2; ++kt) {
#pragma unroll
            for (int rp = 0; rp < 4; rp += 2) {
                float s0 = (kt == 1) ? 0.0f : pm[rp];
                float s1 = (kt == 1) ? 0.0f : pm[rp + 1];
                float o0 = __shfl_xor(s0, 1);
                float o1 = __shfl_xor(s1, 1);
                float lo, hi; int reg;
                if (parity == 0) { lo = s0; hi = o0; reg = rp; }
                else             { lo = o1; hi = s1; reg = rp + 1; }
                unsigned pk = (unsigned)f2bf(lo) | ((unsigned)f2bf(hi) << 16);
                *(unsigned*)&p_s[w][lg * 4 + reg][kt * 16 + (lc & ~1)] = pk;
            }
        }
        __syncthreads();   // p_s + vT_s ready
#pragma unroll
        for (int db = 0; db < 4; ++db) {
#pragma unroll
            for (int reg = 0; reg < 4; ++reg) O[db][reg] *= fac[reg];
        }
        {
            bf16x8 a = *(const bf16x8*)&p_s[w][lc][lg * 8];
#pragma unroll
            for (int db = 0; db < 4; ++db) {
                bf16x8 vb = *(const bf16x8*)&vT_s[db * 16 + lc][lg * 8];
                O[db] = __builtin_amdgcn_mfma_f32_16x16x32_bf16(a, vb, O[db], 0, 0, 0);
            }
        }
    }

    // ---- epilogue: write bf16 h/m splits of attention output ----
#pragma unroll
    for (int db = 0; db < 4; ++db) {
#pragma unroll
        for (int reg = 0; reg < 4; ++reg) {
            int qi = qb + lg * 4 + reg;
            size_t idx2 = ((size_t)(b * S_ + qi)) * D_ + h * DH_ + db * 16 + lc;
            float o = O[db][reg] / lrow[reg];
            unsigned short hb2 = f2bf(o);
            float hf = bf2f(hb2);
            unsigned short mb = f2bf(o - hf);
            AOh[idx2] = (short)hb2;
            AOm[idx2] = (short)mb;
        }
    }
}

// ---------------- launch ----------------
extern "C" void kernel_launch(void* const* d_in, const int* in_sizes, int n_in,
                              void* d_out, int out_size, void* d_ws, size_t ws_size,
                              hipStream_t stream)
{
    const float* X = (const float*)d_in[0];
    const int* amask = (const int*)d_in[1];
    const float* Wq = (const float*)d_in[2];
    const float* Wk = (const float*)d_in[3];
    const float* Wv = (const float*)d_in[4];
    const float* Wo = (const float*)d_in[5];
    float* out = (float*)d_out;

    char* p = (char*)d_ws;
    auto alloc = [&](size_t bytes) -> char* {
        char* r = p; p += (bytes + 255) & ~(size_t)255; return r;
    };
    double* sur = (double*)alloc((size_t)B_ * S_ * sizeof(double));
    float* kacc = (float*)alloc((size_t)2 * BS_ * D_ * sizeof(float));  // kf | kp1; reused by O split-K
    float* events = (float*)alloc((size_t)EVCAP_ * D_ * sizeof(float)); // reused as O partial2
    float* ret = (float*)alloc((size_t)B_ * KT_ * D_ * sizeof(float));
    float* sims = (float*)alloc((size_t)B_ * MEM_ * sizeof(float));
    int* seg_start = (int*)alloc((size_t)B_ * S_ * sizeof(int));
    int* seg_end = (int*)alloc((size_t)B_ * S_ * sizeof(int));
    int* scal = (int*)alloc(64);
    short* qbf = (short*)alloc((size_t)BS_ * D_ * sizeof(short));   // qbf|vbf span reused as O partial3
    short* vbf = (short*)alloc((size_t)BS_ * D_ * sizeof(short));
    short* vbfT = (short*)alloc((size_t)B_ * H_ * DH_ * S_ * sizeof(short));
    short* Xh = (short*)alloc((size_t)BS_ * D_ * sizeof(short));   // reused as AOh
    short* Xm = (short*)alloc((size_t)BS_ * D_ * sizeof(short));   // reused as AOm
    short* Xl = (short*)alloc((size_t)BS_ * D_ * sizeof(short));   // reused as kbf
    short* Wqh = (short*)alloc((size_t)D_ * D_ * sizeof(short));
    short* Wqm = (short*)alloc((size_t)D_ * D_ * sizeof(short));
    short* Wvh = (short*)alloc((size_t)D_ * D_ * sizeof(short));
    short* Wvm = (short*)alloc((size_t)D_ * D_ * sizeof(short));
    short* Woh = (short*)alloc((size_t)D_ * D_ * sizeof(short));
    short* Wom = (short*)alloc((size_t)D_ * D_ * sizeof(short));
    short* Wkh = (short*)alloc((size_t)D_ * D_ * sizeof(short));
    short* Wkm = (short*)alloc((size_t)D_ * D_ * sizeof(short));
    short* Wkl = (short*)alloc((size_t)D_ * D_ * sizeof(short));
    if ((size_t)(p - (char*)d_ws) > ws_size) return;  // insufficient workspace

    float* kf = kacc;
    float* kp1 = kacc + (size_t)BS_ * D_;
    short* kbf = Xl;

    // fused splits: X (4096 blocks) + 4 weights (4 x 1024 blocks)
    {
        SpArgs sa = {};
        sa.X = X; sa.Xh = Xh; sa.Xm = Xm; sa.Xl = Xl;
        sa.W[0] = Wq; sa.Wh[0] = Wqh; sa.Wm[0] = Wqm; sa.Wl[0] = nullptr;
        sa.W[1] = Wk; sa.Wh[1] = Wkh; sa.Wm[1] = Wkm; sa.Wl[1] = Wkl;
        sa.W[2] = Wv; sa.Wh[2] = Wvh; sa.Wm[2] = Wvm; sa.Wl[2] = nullptr;
        sa.W[3] = Wo; sa.Wh[3] = Woh; sa.Wm[3] = Wom; sa.Wl[3] = nullptr;
        sa.nx4 = BS_ * D_ / 4;
        split_all_kernel<<<4096 + 4096, 256, 0, stream>>>(sa);
    }

    // Fused QV + K(split-K 2) GEMM: 256 blocks x 512 thr (256² tiles, 3-buffer pipeline).
    {
        G8Args ga = {};
        ga.A[0][0] = Xm;  ga.A[0][1] = Xh;  ga.A[0][2] = Xh;
        ga.B[0][0] = Wqh; ga.B[0][1] = Wqm; ga.B[0][2] = Wqh;
        ga.outb[0] = qbf;
        ga.A[1][0] = Xm;  ga.A[1][1] = Xh;  ga.A[1][2] = Xh;
        ga.B[1][0] = Wvh; ga.B[1][1] = Wvm; ga.B[1][2] = Wvh;
        ga.outb[1] = vbf;
        ga.A[2][0] = Xh;  ga.A[2][1] = Xm;  ga.A[2][2] = Xm;
        ga.B[2][0] = Wkm; ga.B[2][1] = Wkh; ga.B[2][2] = Wkm;
        ga.outf[2] = kf;
        ga.A[3][0] = Xh;  ga.A[3][1] = Xl;  ga.A[3][2] = Xh;
        ga.B[3][0] = Wkl; ga.B[3][1] = Wkh; ga.B[3][2] = Wkh;
        ga.outf[3] = kp1;
        ga.gsbase[0] = 0; ga.gsbase[1] = 0; ga.gsbase[2] = 0; ga.gsbase[3] = 0;
        ga.nt = 96;
        gemm8<<<256, 512, 0, stream>>>(ga);
    }
    // fused: V transpose (1024 blocks) + K split-K add (4096 blocks)
    fixup_kernel<<<1024 + BS_ * D_ / 4 / 256, 256, 0, stream>>>(vbf, vbfT, kf, kp1, kbf);

    surprise_kernel<<<dim3(S_, B_), 256, 0, stream>>>(kf, sur);
    boundary2_kernel<<<1, 256, 0, stream>>>(sur, seg_start, seg_end, scal);
    seg_means_kernel<<<dim3(S_, B_), 256, 0, stream>>>(kf, events, seg_start, seg_end, scal);
    sims_kernel<<<dim3(MEM_, B_), 256, 0, stream>>>(events, kf, sims, scal);
    topk_kernel<<<B_, 256, 0, stream>>>(events, sims, ret, scal);

    attn_mfma_kernel<<<512, 512, 0, stream>>>(qbf, kbf, vbfT, ret, amask, Xh, Xm);

    // O GEMM: A = attention-output splits (AOm,AOh,AOh), split-K=4 -> 256 blocks
    {
        float* p2 = events;
        float* p3 = (float*)qbf;   // qbf|vbf span (contiguous 16 MB) — dead after attn
        G8Args ga = {};
        for (int g = 0; g < 4; ++g) {
            ga.A[g][0] = Xm;  ga.A[g][1] = Xh;  ga.A[g][2] = Xh;
            ga.B[g][0] = Woh; ga.B[g][1] = Wom; ga.B[g][2] = Woh;
            ga.gsbase[g] = g * 24;
        }
        ga.outf[0] = kf; ga.outf[1] = kp1; ga.outf[2] = p2; ga.outf[3] = p3;
        ga.nt = 24;
        gemm8<<<256, 512, 0, stream>>>(ga);
        addo4_kernel<<<BS_ * D_ / 4 / 256, 256, 0, stream>>>(kf, kp1, p2, p3, out);
    }
}

// Round 20
// 338.720 us; speedup vs baseline: 1.2736x; 1.0117x over previous
//
#include <hip/hip_runtime.h>
#include <math.h>

#define B_ 2
#define S_ 2048
#define H_ 16
#define DH_ 64
#define D_ 1024
#define MEM_ 1000
#define KT_ 10
#define THRESH_ 0.5
#define BS_ (B_ * S_)
#define EVCAP_ (2 * S_)   // max possible events (<= S per sample)

typedef float f32x4 __attribute__((ext_vector_type(4)));
typedef short bf16x8 __attribute__((ext_vector_type(8)));
typedef short s16x4 __attribute__((ext_vector_type(4)));

__device__ inline unsigned short f2bf(float f) {
    union { float f; unsigned u; } v; v.f = f;
    unsigned u = v.u;
    unsigned r = (u + 0x7FFFu + ((u >> 16) & 1u)) >> 16;  // RNE
    return (unsigned short)r;
}
__device__ inline float bf2f(unsigned short h) {
    union { unsigned u; float f; } v; v.u = ((unsigned)h) << 16; return v.f;
}

// async global->LDS, 16B per lane; LDS dest = wave-uniform base + lane*16
__device__ __forceinline__ void gload16(const short* gp, const short* lp) {
    __builtin_amdgcn_global_load_lds(
        (__attribute__((address_space(1))) void*)(unsigned long long)gp,
        (__attribute__((address_space(3))) void*)(unsigned)(unsigned long long)lp,
        16, 0, 0);
}

// ---------------- fused input split: X (h,m,l) + 4 weights in ONE dispatch ----
struct SpArgs {
    const float* X;
    short *Xh, *Xm, *Xl;
    const float* W[4];          // Wq, Wk, Wv, Wo
    short *Wh[4], *Wm[4], *Wl[4];  // Wl null -> skip
    int nx4;                    // X f32x4 count (4096 blocks worth)
};
__global__ __launch_bounds__(256) void split_all_kernel(SpArgs sa)
{
    int bid = blockIdx.x;
    const float* src; short *ph, *pm, *pl; int i;
    if (bid < 4096) {               // X section
        i = bid * 256 + threadIdx.x;
        if (i >= sa.nx4) return;
        src = sa.X; ph = sa.Xh; pm = sa.Xm; pl = sa.Xl;
    } else {                        // weight section: 1024 blocks each
        int wb = bid - 4096;
        int y = wb >> 10;
        i = (wb & 1023) * 256 + threadIdx.x;
        src = sa.W[y]; ph = sa.Wh[y]; pm = sa.Wm[y]; pl = sa.Wl[y];
    }
    float4 x = ((const float4*)src)[i];
    float xs[4] = {x.x, x.y, x.z, x.w};
    s16x4 hv, mv, lv;
    bool wl = (pl != nullptr);
#pragma unroll
    for (int j = 0; j < 4; ++j) {
        unsigned short hb = f2bf(xs[j]);
        float hf = bf2f(hb);
        float r1 = xs[j] - hf;            // exact in f32
        unsigned short mb = f2bf(r1);
        hv[j] = (short)hb; mv[j] = (short)mb;
        if (wl) {
            float mf = bf2f(mb);
            lv[j] = (short)f2bf(r1 - mf); // exact residual, rounded
        }
    }
    ((s16x4*)ph)[i] = hv;
    ((s16x4*)pm)[i] = mv;
    if (wl) ((s16x4*)pl)[i] = lv;
}

// ---------------- 256x256 single-phase split-precision bf16 MFMA GEMM ----------
// BK=32, triple-buffered LDS (96 KiB), counted vmcnt(4). Per tile (R17-exact order):
// 12 ds_read_b128 -> stage(t+2) -> 32 MFMA -> vmcnt -> ONE barrier.
struct G8Args {
    const short* A[4][3];   // per-group A term pointers (term id = gs>>5)
    const short* B[4][3];
    short* outb[4];         // bf16 output (or null)
    float* outf[4];         // f32 output (used when outb[g]==null)
    int gsbase[4];          // global K-step (32-wide) base per group
    int nt;                 // K-tiles per block (>= 2)
};

__global__ __launch_bounds__(512, 2) void gemm8(G8Args ga)
{
    __shared__ __align__(16) short Abuf[3][2][4096];   // [buf][half(128 rows)][packed 128x32]
    __shared__ __align__(16) short Bbuf[3][2][4096];

    int wg = blockIdx.x;
    int lin = (wg & 7) * 32 + (wg >> 3);   // XCD-clustered (256 % 8 == 0 -> bijective)
    int jb = lin >> 4;                     // (g, bcol): 2 per XCD -> B panels L2-resident
    int by = lin & 15;                     // row panel 0..15
    int g = jb >> 2;
    int bcol = jb & 3;

    int tid = threadIdx.x;
    int w = tid >> 6, l = tid & 63;
    int wm = w >> 2, wn = w & 3;           // wave grid 2M x 4N
    int lg = l >> 4, lc = l & 15;

    const short* A0 = ga.A[g][0]; const short* A1 = ga.A[g][1]; const short* A2 = ga.A[g][2];
    const short* B0 = ga.B[g][0]; const short* B1 = ga.B[g][1]; const short* B2 = ga.B[g][2];
    const int gs0 = ga.gsbase[g];
    const int NT = ga.nt;

    const int u = tid;
    const int vswz = (u & 7) ^ ((u >> 3) & 7);
    const int srow = 2 * (u >> 3) + (vswz >> 2);     // 0..127 within half
    const int skcol = (vswz & 3) * 8;                // shorts
    const size_t abase = (size_t)(by * 256) * D_ + skcol;
    const size_t bbase = (size_t)(bcol * 256) * D_ + skcol;
    const int dst0 = w * 512;                        // wave-uniform LDS short offset

    auto STAGE_A = [&](int ts, int d) {
        int tt = ts >> 5; int k0 = (ts & 31) << 5;
        const short* At = (tt == 0) ? A0 : ((tt == 1) ? A1 : A2);
        const short* Ab = At + abase + k0;
#pragma unroll
        for (int h = 0; h < 2; ++h)
            gload16(Ab + (size_t)(h * 128 + srow) * D_, &Abuf[d][h][dst0]);
    };
    auto STAGE_B = [&](int ts, int d) {
        int tt = ts >> 5; int k0 = (ts & 31) << 5;
        const short* Bt = (tt == 0) ? B0 : ((tt == 1) ? B1 : B2);
        const short* Bb = Bt + bbase + k0;
#pragma unroll
        for (int h = 0; h < 2; ++h)
            gload16(Bb + (size_t)(h * 128 + srow) * D_, &Bbuf[d][h][dst0]);
    };

    f32x4 acc[8][4] = {};
    const int psa = (((((lc & 1) << 2) | lg)) ^ ((lc >> 1) & 7)) * 8;
    const int rbase = (lc >> 1) * 64;

    // prologue: stage tiles 0 and 1
    STAGE_A(gs0, 0); STAGE_B(gs0, 0);
    STAGE_A(gs0 + 1, 1); STAGE_B(gs0 + 1, 1);
    asm volatile("s_waitcnt vmcnt(4)" ::: "memory");   // tile 0 landed; tile 1 in flight
    asm volatile("s_barrier" ::: "memory");
    __builtin_amdgcn_sched_barrier(0);

    int d = 0, ds = 2;
    for (int t = 0; t < NT; ++t) {
        const short* Ab0 = &Abuf[d][wm][rbase + psa];
        const short* Bb0 = &Bbuf[d][wn >> 1][(wn & 1) * 2048 + rbase + psa];
        bf16x8 av[8], bv[4];
#pragma unroll
        for (int nf = 0; nf < 4; ++nf) bv[nf] = *(const bf16x8*)&Bb0[nf * 512];
#pragma unroll
        for (int mf = 0; mf < 8; ++mf) av[mf] = *(const bf16x8*)&Ab0[mf * 512];
        if (t + 2 < NT) { STAGE_A(gs0 + t + 2, ds); STAGE_B(gs0 + t + 2, ds); }
        __builtin_amdgcn_s_setprio(1);
#pragma unroll
        for (int mf = 0; mf < 8; ++mf)
#pragma unroll
            for (int nf = 0; nf < 4; ++nf)
                acc[mf][nf] = __builtin_amdgcn_mfma_f32_16x16x32_bf16(av[mf], bv[nf], acc[mf][nf], 0, 0, 0);
        __builtin_amdgcn_s_setprio(0);
        if (t + 2 < NT) asm volatile("s_waitcnt vmcnt(4)" ::: "memory");   // t+1 landed, t+2 in flight
        else            asm volatile("s_waitcnt vmcnt(0)" ::: "memory");   // drain tail
        asm volatile("s_barrier" ::: "memory");
        __builtin_amdgcn_sched_barrier(0);
        d = (d == 2) ? 0 : d + 1;
        ds = (ds == 2) ? 0 : ds + 1;
    }

    // epilogue
    short* ob = ga.outb[g];
    if (ob) {
#pragma unroll
        for (int mf = 0; mf < 8; ++mf)
#pragma unroll
            for (int nf = 0; nf < 4; ++nf)
#pragma unroll
                for (int reg = 0; reg < 4; ++reg) {
                    int row = by * 256 + wm * 128 + mf * 16 + lg * 4 + reg;
                    int col = bcol * 256 + wn * 64 + nf * 16 + lc;
                    ob[(size_t)row * D_ + col] = (short)f2bf(acc[mf][nf][reg]);
                }
    } else {
        float* of = ga.outf[g];
#pragma unroll
        for (int mf = 0; mf < 8; ++mf)
#pragma unroll
            for (int nf = 0; nf < 4; ++nf)
#pragma unroll
                for (int reg = 0; reg < 4; ++reg) {
                    int row = by * 256 + wm * 128 + mf * 16 + lg * 4 + reg;
                    int col = bcol * 256 + wn * 64 + nf * 16 + lc;
                    of[(size_t)row * D_ + col] = acc[mf][nf][reg];
                }
    }
}

// ---------------- fused post-QVK: V transpose + K split-K add (one dispatch) ----
__global__ __launch_bounds__(256) void fixup_kernel(const short* __restrict__ vbf,
                                                    short* __restrict__ vbfT,
                                                    float* __restrict__ kf,
                                                    const float* __restrict__ kp1,
                                                    short* __restrict__ kbf)
{
    int bid = blockIdx.x;
    int tid = threadIdx.x;
    if (bid < 1024) {
        __shared__ short st[64][70];
        int t = bid;
        int s0 = (t & 31) * 64;
        int h = (t >> 5) & 15;
        int b = t >> 9;
        int r = tid >> 2, cb = (tid & 3) * 16;
        const short* src = vbf + (size_t)(b * S_ + s0 + r) * D_ + h * DH_ + cb;
        *(bf16x8*)&st[r][cb] = *(const bf16x8*)src;
        *(bf16x8*)&st[r][cb + 8] = *(const bf16x8*)(src + 8);
        __syncthreads();
        int c = tid >> 2, sb = (tid & 3) * 16;
        short tmp[16];
#pragma unroll
        for (int i = 0; i < 16; ++i) tmp[i] = st[sb + i][c];
        short* dst = vbfT + ((size_t)(b * H_ + h) * DH_ + c) * S_ + s0 + sb;
        *(bf16x8*)dst = *(bf16x8*)&tmp[0];
        *(bf16x8*)(dst + 8) = *(bf16x8*)&tmp[8];
    } else {
        size_t i = (size_t)(bid - 1024) * 256 + tid;
        float4 a = ((const float4*)kf)[i];
        float4 b = ((const float4*)kp1)[i];
        float4 s = {a.x + b.x, a.y + b.y, a.z + b.z, a.w + b.w};
        ((float4*)kf)[i] = s;
        s16x4 o;
        o[0] = (short)f2bf(s.x); o[1] = (short)f2bf(s.y);
        o[2] = (short)f2bf(s.z); o[3] = (short)f2bf(s.w);
        ((s16x4*)kbf)[i] = o;
    }
}

__global__ __launch_bounds__(256) void addo4_kernel(const float* __restrict__ p0,
                                                    const float* __restrict__ p1,
                                                    const float* __restrict__ p2,
                                                    const float* __restrict__ p3,
                                                    float* __restrict__ out)
{
    size_t i = (size_t)blockIdx.x * 256 + threadIdx.x;
    float4 a = ((const float4*)p0)[i];
    float4 b = ((const float4*)p1)[i];
    float4 c = ((const float4*)p2)[i];
    float4 d = ((const float4*)p3)[i];
    float4 s = {((a.x + b.x) + c.x) + d.x, ((a.y + b.y) + c.y) + d.y,
                ((a.z + b.z) + c.z) + d.z, ((a.w + b.w) + c.w) + d.w};
    ((float4*)out)[i] = s;
}

// ---------------- surprise (both batches, 4 rows/block): sur[b][t] = ||kf[t]-kf[t-1]|| ----
__global__ __launch_bounds__(256) void surprise_kernel(const float* __restrict__ kf,
                                                       double* __restrict__ sur)
{
    int b = blockIdx.y;
    const float* kfb = kf + (size_t)b * S_ * D_;
    __shared__ double red[256];
    for (int tt = 0; tt < 4; ++tt) {
        int t = blockIdx.x * 4 + tt;
        if (t == 0) {
            if (threadIdx.x == 0) sur[(size_t)b * S_] = 0.0;
            continue;
        }
        double acc = 0.0;
        for (int d = threadIdx.x; d < D_; d += 256) {
            double df = (double)kfb[(size_t)t * D_ + d] - (double)kfb[(size_t)(t - 1) * D_ + d];
            acc += df * df;
        }
        red[threadIdx.x] = acc;
        __syncthreads();
        for (int s = 128; s > 0; s >>= 1) {
            if (threadIdx.x < s) red[threadIdx.x] += red[threadIdx.x + s];
            __syncthreads();
        }
        if (threadIdx.x == 0) sur[(size_t)b * S_ + t] = sqrt(red[0]);
        __syncthreads();
    }
}

// ---------------- boundaries, one block per batch (grid=2). scal[4+b]=nseg_b.
// evbase_b is computed inline downstream: evb = (b==0) ? 0 : scal[4].
__global__ __launch_bounds__(256) void boundary_par_kernel(const double* __restrict__ sur,
                                                           int* __restrict__ seg_start,
                                                           int* __restrict__ seg_end,
                                                           int* __restrict__ scal)
{
    __shared__ double lsur[S_];
    __shared__ double red[256];
    __shared__ double sh_mean, sh_thr;
    __shared__ int cnt[256];
    int tid = threadIdx.x;
    int b = blockIdx.x;
    for (int t = tid; t < S_; t += 256) lsur[t] = sur[(size_t)b * S_ + t];
    __syncthreads();
    double a = 0.0;
    for (int t = tid; t < S_; t += 256) a += lsur[t];
    red[tid] = a;
    __syncthreads();
    for (int s = 128; s > 0; s >>= 1) {
        if (tid < s) red[tid] += red[tid + s];
        __syncthreads();
    }
    if (tid == 0) sh_mean = red[0] / (double)S_;
    __syncthreads();
    double mean = sh_mean;
    a = 0.0;
    for (int t = tid; t < S_; t += 256) { double d = lsur[t] - mean; a += d * d; }
    red[tid] = a;
    __syncthreads();
    for (int s = 128; s > 0; s >>= 1) {
        if (tid < s) red[tid] += red[tid + s];
        __syncthreads();
    }
    if (tid == 0) sh_thr = mean + THRESH_ * sqrt(red[0] / (double)(S_ - 1));
    __syncthreads();
    double thr = sh_thr;
    bool flg[8];
    int c = 0;
#pragma unroll
    for (int j = 0; j < 8; ++j) {
        int t = tid * 8 + j;
        flg[j] = (lsur[t] > thr) || (t == S_ - 1);
        c += flg[j] ? 1 : 0;
    }
    cnt[tid] = c;
    __syncthreads();
    for (int off = 1; off < 256; off <<= 1) {   // Hillis-Steele inclusive scan
        int v = cnt[tid];
        int add = (tid >= off) ? cnt[tid - off] : 0;
        __syncthreads();
        cnt[tid] = v + add;
        __syncthreads();
    }
    int r = (tid == 0) ? 0 : cnt[tid - 1];
    int* se = seg_end + b * S_;
    int* ss = seg_start + b * S_;
#pragma unroll
    for (int j = 0; j < 8; ++j) {
        if (flg[j]) { se[r] = tid * 8 + j; ++r; }
    }
    __syncthreads();
    int n = cnt[255];
    for (int i = tid; i < n; i += 256)
        ss[i] = (i == 0) ? 0 : se[i - 1] + 1;
    if (tid == 0) scal[4 + b] = n;   // nseg_b
}

// ---------------- segment means BOTH batches -> append events ----------------
__global__ __launch_bounds__(256) void seg_means_kernel(const float* __restrict__ kf,
                                                        float* __restrict__ events,
                                                        const int* __restrict__ seg_start,
                                                        const int* __restrict__ seg_end,
                                                        const int* __restrict__ scal)
{
    int g = blockIdx.x;
    int b = blockIdx.y;
    if (g >= scal[4 + b]) return;
    const float* kfb = kf + (size_t)b * S_ * D_;
    int s = seg_start[b * S_ + g], e = seg_end[b * S_ + g];
    double inv = 1.0 / (double)(e - s + 1);
    int evb = (b == 0) ? 0 : scal[4];
    size_t obase = (size_t)(evb + g) * D_;
    for (int d = threadIdx.x; d < D_; d += 256) {
        double acc = 0.0;
        for (int r = s; r <= e; ++r) acc += (double)kfb[(size_t)r * D_ + d];
        events[obase + d] = (float)(acc * inv);
    }
}

// ---------------- cosine sims BOTH batches vs each batch's last key ----------
__global__ __launch_bounds__(256) void sims_kernel(const float* __restrict__ events,
                                                   const float* __restrict__ kf,
                                                   float* __restrict__ sims,
                                                   const int* __restrict__ scal)
{
    int e = blockIdx.x;
    int b = blockIdx.y;
    int total = (b == 0) ? scal[4] : (scal[4] + scal[5]);   // events appended through batch b
    int w = total < MEM_ ? total : MEM_;
    float* sb = sims + b * MEM_;
    if (e >= w) { if (threadIdx.x == 0) sb[e] = -INFINITY; return; }
    int wstart = total - w;
    const float* ev = events + (size_t)(wstart + e) * D_;
    const float* q = kf + ((size_t)(b * S_ + S_ - 1)) * D_;
    __shared__ double r1[256], r2[256], r3[256];
    int tid = threadIdx.x;
    double dot = 0.0, n2 = 0.0, q2 = 0.0;
    for (int d = tid; d < D_; d += 256) {
        double ed = ev[d], qd = q[d];
        dot += ed * qd; n2 += ed * ed; q2 += qd * qd;
    }
    r1[tid] = dot; r2[tid] = n2; r3[tid] = q2;
    __syncthreads();
    for (int s = 128; s > 0; s >>= 1) {
        if (tid < s) { r1[tid] += r1[tid + s]; r2[tid] += r2[tid + s]; r3[tid] += r3[tid + s]; }
        __syncthreads();
    }
    if (tid == 0) {
        double mn = sqrt(r2[0]); if (mn < 1e-8) mn = 1e-8;
        double qn = sqrt(r3[0]); if (qn < 1e-8) qn = 1e-8;
        sb[e] = (float)(r1[0] / (mn * qn));
    }
}

// ---------------- top-KT BOTH batches (block b) + gather ----------------
__global__ __launch_bounds__(256) void topk_kernel(const float* __restrict__ events,
                                                   float* __restrict__ sims,
                                                   float* __restrict__ ret,
                                                   const int* __restrict__ scal)
{
    int b = blockIdx.x;
    int total = (b == 0) ? scal[4] : (scal[4] + scal[5]);
    int w = total < MEM_ ? total : MEM_;
    int wstart = total - w;
    float* sb = sims + b * MEM_;
    float* retb = ret + (size_t)b * KT_ * D_;
    __shared__ float bv[256];
    __shared__ int bidx[256];
    __shared__ int chosen;
    int tid = threadIdx.x;
    for (int r = 0; r < KT_; ++r) {
        float best = -INFINITY;
        int bi = 0x7fffffff;
        for (int e = tid; e < w; e += 256) {
            float v = sb[e];
            if (v > best || (v == best && e < bi)) { best = v; bi = e; }
        }
        bv[tid] = best; bidx[tid] = bi;
        __syncthreads();
        for (int s = 128; s > 0; s >>= 1) {
            if (tid < s) {
                if (bv[tid + s] > bv[tid] || (bv[tid + s] == bv[tid] && bidx[tid + s] < bidx[tid])) {
                    bv[tid] = bv[tid + s]; bidx[tid] = bidx[tid + s];
                }
            }
            __syncthreads();
        }
        if (tid == 0) {
            chosen = (r < w) ? bidx[0] : -1;
            if (chosen >= 0) sb[chosen] = -INFINITY;
        }
        __syncthreads();
        int c = chosen;
        if (c >= 0) {
            const float* ev = events + (size_t)(wstart + c) * D_;
            for (int d = tid; d < D_; d += 256) retb[(size_t)r * D_ + d] = ev[d];
        } else {
            for (int d = tid; d < D_; d += 256) retb[(size_t)r * D_ + d] = 0.0f;
        }
        __syncthreads();
    }
}

// ---------------- attention: bf16 MFMA flash, QTT=128, KTT=128, peeled memtile ----
#define QTT 128
#define KTT 128
__global__ __launch_bounds__(512, 4) void attn_mfma_kernel(const short* __restrict__ qbf,
                                                           const short* __restrict__ kbf,
                                                           const short* __restrict__ vbfT,
                                                           const float* __restrict__ ret,
                                                           const int* __restrict__ amask,
                                                           short* __restrict__ AOh,
                                                           short* __restrict__ AOm)
{
    __shared__ __align__(16) short k_s[KTT][72];       // [key][d]   (row 144B)
    __shared__ __align__(16) short vT_s[DH_][136];     // [d][key]   (row 272B)
    __shared__ __align__(16) short p_s[8][16][136];    // per-wave [q][key]

    const float LOG2E = 1.4426950408889634f;
    int bid = blockIdx.x;                    // 0..511
    int xcd = bid & 7;
    int idx = bid >> 3;                      // 0..63
    int qtslot = idx >> 2;                   // 0..15
    int hbL = idx & 3;                       // 0..3
    int qt = (qtslot < 8) ? (15 - qtslot) : (qtslot - 8);
    int hb = xcd * 4 + hbL;                  // 0..31
    int h = hb & 15, b = hb >> 4;
    int q0 = qt * QTT;

    int tid = threadIdx.x;
    int w = tid >> 6, l = tid & 63;          // 8 waves
    int lg = l >> 4, lc = l & 15;
    int qb = q0 + w * 16;                    // this wave's 16 queries
    float scale2 = 0.125f * LOG2E;
    float slope2 = exp2f(-0.5f * (float)(h + 1)) * LOG2E;

    bf16x8 qfr[2];
#pragma unroll
    for (int half = 0; half < 2; ++half)
        qfr[half] = *(const bf16x8*)(qbf + ((size_t)(b * S_ + qb + lc)) * D_ + h * DH_ + half * 32 + lg * 8);

    float mrow[4], lrow[4], fac[4];
#pragma unroll
    for (int r = 0; r < 4; ++r) { mrow[r] = -INFINITY; lrow[r] = 0.0f; }
    f32x4 O[4] = {};

    // main-loop staging indices
    int skr = tid >> 2;             // K stage: key row 0..127
    int skc = (tid & 3) * 16;       // K stage: d col base (16 shorts)
    int sdv = tid >> 3;             // V stage: d row 0..63
    int skk = (tid & 7) * 16;       // V stage: key col base (16 shorts)

    const short* kptr = kbf + ((size_t)(b * S_ + skr)) * D_ + h * DH_ + skc;
    const short* vptr = vbfT + ((size_t)(b * H_ + h) * DH_ + sdv) * S_ + skk;

    int ntiles = qt + 1;            // K-tiles of 128 keys
    bf16x8 kr0 = *(const bf16x8*)kptr, kr1 = *(const bf16x8*)(kptr + 8);
    bf16x8 vr0 = *(const bf16x8*)vptr, vr1 = *(const bf16x8*)(vptr + 8);

    for (int tile = 0; tile < ntiles; ++tile) {
        int j0 = tile * KTT;
        __syncthreads();   // all readers of previous tile done
        *(bf16x8*)&k_s[skr][skc] = kr0;
        *(bf16x8*)&k_s[skr][skc + 8] = kr1;
        *(bf16x8*)&vT_s[sdv][skk] = vr0;
        *(bf16x8*)&vT_s[sdv][skk + 8] = vr1;
        __syncthreads();   // tile visible
        if (tile + 1 < ntiles) {   // prefetch next tile (latency hidden under compute)
            const short* kp = kptr + (size_t)(tile + 1) * KTT * D_;
            kr0 = *(const bf16x8*)kp; kr1 = *(const bf16x8*)(kp + 8);
            const short* vp = vptr + (tile + 1) * KTT;
            vr0 = *(const bf16x8*)vp; vr1 = *(const bf16x8*)(vp + 8);
        }

        // ---- QK^T scores (log2 domain), 8 key-groups of 16 ----
        float sc[8][4];
        int am[8];
#pragma unroll
        for (int kt = 0; kt < 8; ++kt) am[kt] = amask[b * S_ + j0 + kt * 16 + lc];
        bool fullvis = (j0 + (KTT - 1) <= qb);   // wave-uniform
#pragma unroll
        for (int kt = 0; kt < 8; ++kt) {
            f32x4 s = {0.0f, 0.0f, 0.0f, 0.0f};
            bf16x8 k0 = *(const bf16x8*)&k_s[kt * 16 + lc][lg * 8];
            bf16x8 k1 = *(const bf16x8*)&k_s[kt * 16 + lc][32 + lg * 8];
            s = __builtin_amdgcn_mfma_f32_16x16x32_bf16(qfr[0], k0, s, 0, 0, 0);
            s = __builtin_amdgcn_mfma_f32_16x16x32_bf16(qfr[1], k1, s, 0, 0, 0);
            int jg = j0 + kt * 16 + lc;
            if (fullvis) {
#pragma unroll
                for (int reg = 0; reg < 4; ++reg) {
                    int qi = qb + lg * 4 + reg;
                    sc[kt][reg] = (am[kt] > 0) ? (s[reg] * scale2 - slope2 * (float)(qi - jg)) : -INFINITY;
                }
            } else {
#pragma unroll
                for (int reg = 0; reg < 4; ++reg) {
                    int qi = qb + lg * 4 + reg;
                    bool vis = (jg <= qi) && (am[kt] > 0);
                    sc[kt][reg] = vis ? (s[reg] * scale2 - slope2 * (float)(qi - jg)) : -INFINITY;
                }
            }
        }

        // ---- online softmax (log2 domain); sc overwritten with P in-place ----
#pragma unroll
        for (int reg = 0; reg < 4; ++reg) {
            float tm = fmaxf(fmaxf(fmaxf(sc[0][reg], sc[1][reg]), fmaxf(sc[2][reg], sc[3][reg])),
                             fmaxf(fmaxf(sc[4][reg], sc[5][reg]), fmaxf(sc[6][reg], sc[7][reg])));
#pragma unroll
            for (int msk = 1; msk <= 8; msk <<= 1) tm = fmaxf(tm, __shfl_xor(tm, msk));
            float mnew = fmaxf(mrow[reg], tm);
            fac[reg] = exp2f(mrow[reg] - mnew);
            mrow[reg] = mnew;
            float rs = 0.0f;
#pragma unroll
            for (int kt = 0; kt < 8; ++kt) {
                float p = exp2f(sc[kt][reg] - mnew);
                sc[kt][reg] = p;
                rs += p;
            }
#pragma unroll
            for (int msk = 1; msk <= 8; msk <<= 1) rs += __shfl_xor(rs, msk);
            lrow[reg] = lrow[reg] * fac[reg] + rs;
        }

        // ---- write P to per-wave LDS as bf16 pairs ----
        int parity = l & 1;
#pragma unroll
        for (int kt = 0; kt < 8; ++kt) {
#pragma unroll
            for (int rp = 0; rp < 4; rp += 2) {
                float s0 = sc[kt][rp];
                float s1 = sc[kt][rp + 1];
                float o0 = __shfl_xor(s0, 1);
                float o1 = __shfl_xor(s1, 1);
                float lo, hi; int reg;
                if (parity == 0) { lo = s0; hi = o0; reg = rp; }
                else             { lo = o1; hi = s1; reg = rp + 1; }
                unsigned pk = (unsigned)f2bf(lo) | ((unsigned)f2bf(hi) << 16);
                *(unsigned*)&p_s[w][lg * 4 + reg][kt * 16 + (lc & ~1)] = pk;
            }
        }
        __syncthreads();   // p_s ready

        // ---- PV accumulate (4 key-halves of 32) ----
#pragma unroll
        for (int db = 0; db < 4; ++db) {
#pragma unroll
            for (int reg = 0; reg < 4; ++reg) O[db][reg] *= fac[reg];
        }
#pragma unroll
        for (int kh = 0; kh < 4; ++kh) {
            bf16x8 a = *(const bf16x8*)&p_s[w][lc][kh * 32 + lg * 8];
#pragma unroll
            for (int db = 0; db < 4; ++db) {
                bf16x8 vb = *(const bf16x8*)&vT_s[db * 16 + lc][kh * 32 + lg * 8];
                O[db] = __builtin_amdgcn_mfma_f32_16x16x32_bf16(a, vb, O[db], 0, 0, 0);
            }
        }
    }

    // ================= peeled memory tile (10 retrieved events) =================
    {
        int sr = tid >> 3;              // 0..63
        int sc0 = (tid & 7) * 8;        // 0..56
        __syncthreads();   // PV readers of last real tile done
        short kv[8];
        if (sr < KT_) {
            const float* rp = ret + ((size_t)(b * KT_ + sr)) * D_ + h * DH_ + sc0;
            float4 a0 = *(const float4*)rp;
            float4 a1 = *(const float4*)(rp + 4);
            kv[0] = (short)f2bf(a0.x); kv[1] = (short)f2bf(a0.y);
            kv[2] = (short)f2bf(a0.z); kv[3] = (short)f2bf(a0.w);
            kv[4] = (short)f2bf(a1.x); kv[5] = (short)f2bf(a1.y);
            kv[6] = (short)f2bf(a1.z); kv[7] = (short)f2bf(a1.w);
        } else {
#pragma unroll
            for (int i = 0; i < 8; ++i) kv[i] = 0;
        }
        *(bf16x8*)&k_s[sr][sc0] = *(bf16x8*)&kv[0];
        __syncthreads();   // k_s ready
        short tv[8];
#pragma unroll
        for (int i = 0; i < 8; ++i) {
            int key = sc0 + i;
            tv[i] = (key < KT_) ? k_s[key][sr] : (short)0;
        }
        *(bf16x8*)&vT_s[sr][sc0] = *(bf16x8*)&tv[0];   // visible by p_s barrier below

        float scm[4];
        {
            f32x4 s = {0.0f, 0.0f, 0.0f, 0.0f};
            bf16x8 k0 = *(const bf16x8*)&k_s[lc][lg * 8];
            bf16x8 k1 = *(const bf16x8*)&k_s[lc][32 + lg * 8];
            s = __builtin_amdgcn_mfma_f32_16x16x32_bf16(qfr[0], k0, s, 0, 0, 0);
            s = __builtin_amdgcn_mfma_f32_16x16x32_bf16(qfr[1], k1, s, 0, 0, 0);
#pragma unroll
            for (int reg = 0; reg < 4; ++reg)
                scm[reg] = (lc < KT_) ? s[reg] * scale2 : -INFINITY;
        }
        float pm[4];
#pragma unroll
        for (int reg = 0; reg < 4; ++reg) {
            float tm = scm[reg];
#pragma unroll
            for (int msk = 1; msk <= 8; msk <<= 1) tm = fmaxf(tm, __shfl_xor(tm, msk));
            float mnew = fmaxf(mrow[reg], tm);
            fac[reg] = exp2f(mrow[reg] - mnew);
            mrow[reg] = mnew;
            float p = exp2f(scm[reg] - mnew);
            pm[reg] = p;
            float rs = p;
#pragma unroll
            for (int msk = 1; msk <= 8; msk <<= 1) rs += __shfl_xor(rs, msk);
            lrow[reg] = lrow[reg] * fac[reg] + rs;
        }
        int parity = l & 1;
#pragma unroll
        for (int kt = 0; kt < 2; ++kt) {
#pragma unroll
            for (int rp = 0; rp < 4; rp += 2) {
                float s0 = (kt == 1) ? 0.0f : pm[rp];
                float s1 = (kt == 1) ? 0.0f : pm[rp + 1];
                float o0 = __shfl_xor(s0, 1);
                float o1 = __shfl_xor(s1, 1);
                float lo, hi; int reg;
                if (parity == 0) { lo = s0; hi = o0; reg = rp; }
                else             { lo = o1; hi = s1; reg = rp + 1; }
                unsigned pk = (unsigned)f2bf(lo) | ((unsigned)f2bf(hi) << 16);
                *(unsigned*)&p_s[w][lg * 4 + reg][kt * 16 + (lc & ~1)] = pk;
            }
        }
        __syncthreads();   // p_s + vT_s ready
#pragma unroll
        for (int db = 0; db < 4; ++db) {
#pragma unroll
            for (int reg = 0; reg < 4; ++reg) O[db][reg] *= fac[reg];
        }
        {
            bf16x8 a = *(const bf16x8*)&p_s[w][lc][lg * 8];
#pragma unroll
            for (int db = 0; db < 4; ++db) {
                bf16x8 vb = *(const bf16x8*)&vT_s[db * 16 + lc][lg * 8];
                O[db] = __builtin_amdgcn_mfma_f32_16x16x32_bf16(a, vb, O[db], 0, 0, 0);
            }
        }
    }

    // ---- epilogue: write bf16 h/m splits of attention output ----
#pragma unroll
    for (int db = 0; db < 4; ++db) {
#pragma unroll
        for (int reg = 0; reg < 4; ++reg) {
            int qi = qb + lg * 4 + reg;
            size_t idx2 = ((size_t)(b * S_ + qi)) * D_ + h * DH_ + db * 16 + lc;
            float o = O[db][reg] / lrow[reg];
            unsigned short hb2 = f2bf(o);
            float hf = bf2f(hb2);
            unsigned short mb = f2bf(o - hf);
            AOh[idx2] = (short)hb2;
            AOm[idx2] = (short)mb;
        }
    }
}

// ---------------- launch ----------------
extern "C" void kernel_launch(void* const* d_in, const int* in_sizes, int n_in,
                              void* d_out, int out_size, void* d_ws, size_t ws_size,
                              hipStream_t stream)
{
    const float* X = (const float*)d_in[0];
    const int* amask = (const int*)d_in[1];
    const float* Wq = (const float*)d_in[2];
    const float* Wk = (const float*)d_in[3];
    const float* Wv = (const float*)d_in[4];
    const float* Wo = (const float*)d_in[5];
    float* out = (float*)d_out;

    char* p = (char*)d_ws;
    auto alloc = [&](size_t bytes) -> char* {
        char* r = p; p += (bytes + 255) & ~(size_t)255; return r;
    };
    double* sur = (double*)alloc((size_t)B_ * S_ * sizeof(double));
    float* kacc = (float*)alloc((size_t)2 * BS_ * D_ * sizeof(float));  // kf | kp1; reused by O split-K
    float* events = (float*)alloc((size_t)EVCAP_ * D_ * sizeof(float)); // reused as O partial2
    float* ret = (float*)alloc((size_t)B_ * KT_ * D_ * sizeof(float));
    float* sims = (float*)alloc((size_t)B_ * MEM_ * sizeof(float));
    int* seg_start = (int*)alloc((size_t)B_ * S_ * sizeof(int));
    int* seg_end = (int*)alloc((size_t)B_ * S_ * sizeof(int));
    int* scal = (int*)alloc(64);
    short* qbf = (short*)alloc((size_t)BS_ * D_ * sizeof(short));   // qbf|vbf span reused as O partial3
    short* vbf = (short*)alloc((size_t)BS_ * D_ * sizeof(short));
    short* vbfT = (short*)alloc((size_t)B_ * H_ * DH_ * S_ * sizeof(short));
    short* Xh = (short*)alloc((size_t)BS_ * D_ * sizeof(short));   // reused as AOh
    short* Xm = (short*)alloc((size_t)BS_ * D_ * sizeof(short));   // reused as AOm
    short* Xl = (short*)alloc((size_t)BS_ * D_ * sizeof(short));   // reused as kbf
    short* Wqh = (short*)alloc((size_t)D_ * D_ * sizeof(short));
    short* Wqm = (short*)alloc((size_t)D_ * D_ * sizeof(short));
    short* Wvh = (short*)alloc((size_t)D_ * D_ * sizeof(short));
    short* Wvm = (short*)alloc((size_t)D_ * D_ * sizeof(short));
    short* Woh = (short*)alloc((size_t)D_ * D_ * sizeof(short));
    short* Wom = (short*)alloc((size_t)D_ * D_ * sizeof(short));
    short* Wkh = (short*)alloc((size_t)D_ * D_ * sizeof(short));
    short* Wkm = (short*)alloc((size_t)D_ * D_ * sizeof(short));
    short* Wkl = (short*)alloc((size_t)D_ * D_ * sizeof(short));
    if ((size_t)(p - (char*)d_ws) > ws_size) return;  // insufficient workspace

    float* kf = kacc;
    float* kp1 = kacc + (size_t)BS_ * D_;
    short* kbf = Xl;

    // fused splits: X (4096 blocks) + 4 weights (4 x 1024 blocks)
    {
        SpArgs sa = {};
        sa.X = X; sa.Xh = Xh; sa.Xm = Xm; sa.Xl = Xl;
        sa.W[0] = Wq; sa.Wh[0] = Wqh; sa.Wm[0] = Wqm; sa.Wl[0] = nullptr;
        sa.W[1] = Wk; sa.Wh[1] = Wkh; sa.Wm[1] = Wkm; sa.Wl[1] = Wkl;
        sa.W[2] = Wv; sa.Wh[2] = Wvh; sa.Wm[2] = Wvm; sa.Wl[2] = nullptr;
        sa.W[3] = Wo; sa.Wh[3] = Woh; sa.Wm[3] = Wom; sa.Wl[3] = nullptr;
        sa.nx4 = BS_ * D_ / 4;
        split_all_kernel<<<4096 + 4096, 256, 0, stream>>>(sa);
    }

    // Fused QV + K(split-K 2) GEMM: 256 blocks x 512 thr (256² tiles, 3-buffer pipeline).
    {
        G8Args ga = {};
        ga.A[0][0] = Xm;  ga.A[0][1] = Xh;  ga.A[0][2] = Xh;
        ga.B[0][0] = Wqh; ga.B[0][1] = Wqm; ga.B[0][2] = Wqh;
        ga.outb[0] = qbf;
        ga.A[1][0] = Xm;  ga.A[1][1] = Xh;  ga.A[1][2] = Xh;
        ga.B[1][0] = Wvh; ga.B[1][1] = Wvm; ga.B[1][2] = Wvh;
        ga.outb[1] = vbf;
        ga.A[2][0] = Xh;  ga.A[2][1] = Xm;  ga.A[2][2] = Xm;
        ga.B[2][0] = Wkm; ga.B[2][1] = Wkh; ga.B[2][2] = Wkm;
        ga.outf[2] = kf;
        ga.A[3][0] = Xh;  ga.A[3][1] = Xl;  ga.A[3][2] = Xh;
        ga.B[3][0] = Wkl; ga.B[3][1] = Wkh; ga.B[3][2] = Wkh;
        ga.outf[3] = kp1;
        ga.gsbase[0] = 0; ga.gsbase[1] = 0; ga.gsbase[2] = 0; ga.gsbase[3] = 0;
        ga.nt = 96;
        gemm8<<<256, 512, 0, stream>>>(ga);
    }
    // fused: V transpose (1024 blocks) + K split-K add (4096 blocks)
    fixup_kernel<<<1024 + BS_ * D_ / 4 / 256, 256, 0, stream>>>(vbf, vbfT, kf, kp1, kbf);

    surprise_kernel<<<dim3(S_ / 4, B_), 256, 0, stream>>>(kf, sur);
    boundary_par_kernel<<<B_, 256, 0, stream>>>(sur, seg_start, seg_end, scal);
    seg_means_kernel<<<dim3(S_, B_), 256, 0, stream>>>(kf, events, seg_start, seg_end, scal);
    sims_kernel<<<dim3(MEM_, B_), 256, 0, stream>>>(events, kf, sims, scal);
    topk_kernel<<<B_, 256, 0, stream>>>(events, sims, ret, scal);

    attn_mfma_kernel<<<512, 512, 0, stream>>>(qbf, kbf, vbfT, ret, amask, Xh, Xm);

    // O GEMM: A = attention-output splits (AOm,AOh,AOh), split-K=4 -> 256 blocks
    {
        float* p2 = events;
        float* p3 = (float*)qbf;   // qbf|vbf span (contiguous 16 MB) — dead after attn
        G8Args ga = {};
        for (int g = 0; g < 4; ++g) {
            ga.A[g][0] = Xm;  ga.A[g][1] = Xh;  ga.A[g][2] = Xh;
            ga.B[g][0] = Woh; ga.B[g][1] = Wom; ga.B[g][2] = Woh;
            ga.gsbase[g] = g * 24;
        }
        ga.outf[0] = kf; ga.outf[1] = kp1; ga.outf[2] = p2; ga.outf[3] = p3;
        ga.nt = 24;
        gemm8<<<256, 512, 0, stream>>>(ga);
        addo4_kernel<<<BS_ * D_ / 4 / 256, 256, 0, stream>>>(kf, kp1, p2, p3, out);
    }
}